// Round 9
// baseline (349.128 us; speedup 1.0000x reference)
//
#include <hip/hip_runtime.h>

#define B   32
#define L   1024
#define MN  512
#define SD  256
#define VD  64
#define DM  256
#define D3  192
#define NH  8
#define DK  32
#define RMAX 30
#define NREL 61
#define SPAD 518   // MN + 6 (3-zero pad each side) for im2col conv windows

typedef __attribute__((ext_vector_type(8))) __bf16 bf16x8;
typedef __attribute__((ext_vector_type(4))) float  f32x4;

static __device__ __forceinline__ ushort f2bf(float f) {
  unsigned u = __float_as_uint(f);
  unsigned r = (u + 0x7FFFu + ((u >> 16) & 1u)) >> 16;
  return (ushort)r;
}
static __device__ __forceinline__ bf16x8 ldbf8(const ushort* p) {
  return __builtin_bit_cast(bf16x8, *(const uint4*)p);
}
static __device__ __forceinline__ float fexp2(float x) {
  return __builtin_amdgcn_exp2f(x);
}

// ---------------------------------------------------------------------------
// prep: tobf5 + splitpad + wbig + possum fused (all input-only readers).
// grid = 240 + 4144 + 192 + 512 = 5088 blocks x 256 threads.
// ---------------------------------------------------------------------------
__global__ __launch_bounds__(256) void prep_kernel(
    const float* __restrict__ Wg, ushort* __restrict__ Wgb,
    const float* __restrict__ Wq, ushort* __restrict__ Wqb,
    const float* __restrict__ Wk, ushort* __restrict__ Wkb,
    const float* __restrict__ Wv, ushort* __restrict__ Wvb,
    const float* __restrict__ fcw, ushort* __restrict__ fcwb,
    const float* __restrict__ xv, ushort* __restrict__ xp,
    const float* __restrict__ w3, const float* __restrict__ w5,
    const float* __restrict__ w7, ushort* __restrict__ wb,
    const float* __restrict__ emb, float* __restrict__ psum) {
  int blk = blockIdx.x;
  if (blk < 240) {
    const float* s; ushort* d; int base;
    if (blk < 16)       { s = Wg;  d = Wgb;  base = blk; }
    else if (blk < 80)  { s = Wq;  d = Wqb;  base = blk - 16; }
    else if (blk < 128) { s = Wk;  d = Wkb;  base = blk - 80; }
    else if (blk < 176) { s = Wv;  d = Wvb;  base = blk - 128; }
    else                { s = fcw; d = fcwb; base = blk - 176; }
    int i = (base * 256 + threadIdx.x) * 4;
    float4 v = *(const float4*)(s + i);
    *(ushort4*)(d + i) = make_ushort4(f2bf(v.x), f2bf(v.y), f2bf(v.z), f2bf(v.w));
  } else if (blk < 240 + 4144) {
    int i = (blk - 240) * 256 + threadIdx.x;
    if (i < B * SPAD * VD) {
      int c = i & 63;
      int bp = i >> 6;
      int b_ = bp / SPAD, p = bp - b_ * SPAD;
      int s = p - 3;
      float v = (s >= 0 && s < MN) ? xv[((size_t)b_ * MN + s) * VD + c] : 0.f;
      ushort hi = f2bf(v);
      float vh = __uint_as_float((uint)hi << 16);
      ushort lo = f2bf(v - vh);
      xp[i] = hi;
      xp[(size_t)B * SPAD * VD + i] = lo;
    }
  } else if (blk < 240 + 4144 + 192) {
    const int o = blk - (240 + 4144);     // 0..191
    const int scale = o >> 6, oo = o & 63;
    for (int j = threadIdx.x; j < 448; j += 256) {
      const int k7 = j >> 6, i = j & 63;
      float v = 0.f;
      if (scale == 0) {
        int k = k7 - 2; if (k >= 0 && k < 3) v = w3[((size_t)oo * VD + i) * 3 + k];
      } else if (scale == 1) {
        int k = k7 - 1; if (k >= 0 && k < 5) v = w5[((size_t)oo * VD + i) * 5 + k];
      } else {
        v = w7[((size_t)oo * VD + i) * 7 + k7];
      }
      wb[(size_t)o * 448 + j] = f2bf(v);
    }
  } else {
    const int j = blk - (240 + 4144 + 192);  // 0..511
    const int d = threadIdx.x;
    if (d < D3) {
      float acc = 0.f;
      for (int r = 0; r < NREL; ++r) {
        int v = r - RMAX;
        int cnt;
        if (r == 0)             cnt = max(0, MN - (j + RMAX));
        else if (r == NREL - 1) cnt = max(0, j - RMAX + 1);
        else                    cnt = (j - v >= 0 && j - v < MN) ? 1 : 0;
        acc += (float)cnt * emb[(size_t)r * D3 + d];
      }
      psum[(size_t)j * D3 + d] = acc;
    }
  }
}

// ---------------------------------------------------------------------------
// Shared MFMA projection body: 16 rows/wave, 16 col-tiles, CIN/32 k-steps.
// OMODE: 0 = f32 [row][DM] (sigmoid); 4 = bf16 Q head-major [b][h][q][dk]
// ---------------------------------------------------------------------------
template<int CIN, int OMODE, int ACT, int AF32>
static __device__ __forceinline__ void proj_body(
    int blk, const void* __restrict__ Xv, const ushort* __restrict__ Wb,
    void* __restrict__ Yv, int tid) {
  const int wave = tid >> 6, lane = tid & 63;
  const int q15 = lane & 15, quad = lane >> 4;
  const int row0 = blk * 64 + wave * 16;
  constexpr int KS = CIN / 32;

  f32x4 acc[16];
#pragma unroll
  for (int t = 0; t < 16; ++t) acc[t] = (f32x4){0.f, 0.f, 0.f, 0.f};

  const ushort* abase = (const ushort*)Xv + (size_t)(row0 + q15) * CIN + quad * 8;
  const float*  fbase = (const float*)Xv + (size_t)(row0 + q15) * CIN + quad * 8;
  const ushort* bbase = Wb + (size_t)q15 * CIN + quad * 8;
#pragma unroll 2
  for (int ks = 0; ks < KS; ++ks) {
    bf16x8 af;
    if constexpr (AF32) {
      float4 u0 = *(const float4*)(fbase + ks * 32);
      float4 u1 = *(const float4*)(fbase + ks * 32 + 4);
      uint4 p;
      p.x = (uint)f2bf(u0.x) | ((uint)f2bf(u0.y) << 16);
      p.y = (uint)f2bf(u0.z) | ((uint)f2bf(u0.w) << 16);
      p.z = (uint)f2bf(u1.x) | ((uint)f2bf(u1.y) << 16);
      p.w = (uint)f2bf(u1.z) | ((uint)f2bf(u1.w) << 16);
      af = __builtin_bit_cast(bf16x8, p);
    } else {
      af = ldbf8(abase + ks * 32);
    }
#pragma unroll
    for (int t = 0; t < 16; ++t) {
      bf16x8 bf = ldbf8(bbase + (size_t)t * 16 * CIN + ks * 32);
      acc[t] = __builtin_amdgcn_mfma_f32_16x16x32_bf16(af, bf, acc[t], 0, 0, 0);
    }
  }
#pragma unroll
  for (int reg = 0; reg < 4; ++reg) {
    const int row = row0 + quad * 4 + reg;
#pragma unroll
    for (int t = 0; t < 16; ++t) {
      int col = t * 16 + q15;
      float v = acc[t][reg];
      if (ACT == 1) v = 1.f / (1.f + __expf(-v));
      if (OMODE == 0) {
        ((float*)Yv)[(size_t)row * DM + col] = v;
      } else {
        int b_ = row >> 10, q = row & 1023;
        int h = col >> 5, dk = col & 31;
        ((ushort*)Yv)[((size_t)((b_ * NH + h) * L + q)) * DK + dk] = f2bf(v);
      }
    }
  }
}

// ---------------------------------------------------------------------------
// conv GEMM body (32 rows/block, halves weight re-fetch vs 16-row): 512 blks.
// ---------------------------------------------------------------------------
static __device__ __forceinline__ void conv_body(
    int blk, const ushort* __restrict__ Xp, const ushort* __restrict__ Wb,
    const float* __restrict__ b3, const float* __restrict__ b5,
    const float* __restrict__ b7, float* __restrict__ xm, int tid) {
  const int wave = tid >> 6, lane = tid & 63;
  const int q15 = lane & 15, quad = lane >> 4;
  const int row0 = blk * 32;
  const int b_ = row0 >> 9, s0 = row0 & 511;

  f32x4 acc0[3], acc1[3];
#pragma unroll
  for (int t = 0; t < 3; ++t) {
    acc0[t] = (f32x4){0.f, 0.f, 0.f, 0.f};
    acc1[t] = (f32x4){0.f, 0.f, 0.f, 0.f};
  }
  const ushort* h0 = Xp + ((size_t)b_ * SPAD + s0 + q15) * VD + quad * 8;
  const ushort* h1 = h0 + 16 * VD;
  const ushort* l0 = h0 + (size_t)B * SPAD * VD;
  const ushort* l1 = l0 + 16 * VD;
  const ushort* wbase = Wb + ((size_t)wave * 48 + q15) * 448 + quad * 8;

#pragma unroll 2
  for (int ks = 0; ks < 14; ++ks) {
    bf16x8 ah0 = ldbf8(h0 + ks * 32), al0 = ldbf8(l0 + ks * 32);
    bf16x8 ah1 = ldbf8(h1 + ks * 32), al1 = ldbf8(l1 + ks * 32);
#pragma unroll
    for (int t = 0; t < 3; ++t) {
      bf16x8 bf = ldbf8(wbase + (size_t)t * 16 * 448 + ks * 32);
      acc0[t] = __builtin_amdgcn_mfma_f32_16x16x32_bf16(ah0, bf, acc0[t], 0, 0, 0);
      acc0[t] = __builtin_amdgcn_mfma_f32_16x16x32_bf16(al0, bf, acc0[t], 0, 0, 0);
      acc1[t] = __builtin_amdgcn_mfma_f32_16x16x32_bf16(ah1, bf, acc1[t], 0, 0, 0);
      acc1[t] = __builtin_amdgcn_mfma_f32_16x16x32_bf16(al1, bf, acc1[t], 0, 0, 0);
    }
  }
#pragma unroll
  for (int t = 0; t < 3; ++t) {
    const int col = (wave * 3 + t) * 16 + q15;
    const float bias = col < 64 ? b3[col] : (col < 128 ? b5[col - 64] : b7[col - 128]);
#pragma unroll
    for (int reg = 0; reg < 4; ++reg) {
      const int row = row0 + quad * 4 + reg;
      xm[(size_t)row * D3 + col] = acc0[t][reg] + bias;
      xm[(size_t)(row + 16) * D3 + col] = acc1[t][reg] + bias;
    }
  }
}

// ---------------------------------------------------------------------------
// R16 mega1: conv (512) | Gamma (256) | Q (512) — mutually independent
// stages co-scheduled in one 1280-block launch.
// ---------------------------------------------------------------------------
__global__ __launch_bounds__(256, 2) void mega1_kernel(
    const ushort* __restrict__ Xp, const ushort* __restrict__ Wbig,
    const float* __restrict__ b3, const float* __restrict__ b5,
    const float* __restrict__ b7, float* __restrict__ xm,
    const float* __restrict__ xv, const ushort* __restrict__ Wgb,
    float* __restrict__ Gamma,
    const float* __restrict__ xs, const ushort* __restrict__ Wqb,
    ushort* __restrict__ Qb) {
  const int blk = blockIdx.x;
  const int tid = threadIdx.x;
  if (blk < 512) {
    conv_body(blk, Xp, Wbig, b3, b5, b7, xm, tid);
  } else if (blk < 768) {
    proj_body<VD, 0, 1, 1>(blk - 512, xv, Wgb, Gamma, tid);
  } else {
    proj_body<SD, 4, 0, 1>(blk - 768, xs, Wqb, Qb, tid);
  }
}

// ---------------------------------------------------------------------------
// R16 projkv_pe: K+V projection with block-local rel-pos-enc into LDS.
// Each block covers 64 rows; 256 threads compute PE for 64x192 elems into
// LDS (bf16, identical f2bf rounding as the old pe4 -> bit-identical A),
// then 4 waves run the 16-row MFMA projection reading A from LDS.
// Deletes the pe4 launch + xpeb round-trip. blk<256: K; else V.
// ---------------------------------------------------------------------------
#define PPAD 200   // LDS row pitch (ushorts): 400B rows, 16B-aligned
__global__ __launch_bounds__(256, 2) void projkv_pe_kernel(
    const float* __restrict__ xm, const float* __restrict__ psum,
    const float* __restrict__ emb, const float* __restrict__ dww,
    const float* __restrict__ dwb, const ushort* __restrict__ Wkb,
    const ushort* __restrict__ Wvb, ushort* __restrict__ Kp,
    ushort* __restrict__ Vt) {
  const int isV = blockIdx.x >> 8;
  const int blk = blockIdx.x & 255;
  const int tid = threadIdx.x;
  const int row0 = blk * 64;

  __shared__ ushort pes[64][PPAD];

  // cooperative PE fill: 64 rows x 192 cols, float4 granularity
#pragma unroll 2
  for (int it = 0; it < 12; ++it) {
    int f = it * 256 + tid;            // 0..3071
    int r = f / 48, c4 = (f % 48) * 4;
    int grow = row0 + r;
    int j = grow & 511;
    const float* arow = xm + (size_t)grow * D3 + c4;
    f32x4 xc = *(const f32x4*)(arow);
    f32x4 xl = (j > 0)      ? *(const f32x4*)(arow - D3) : (f32x4){0.f, 0.f, 0.f, 0.f};
    f32x4 xr = (j < MN - 1) ? *(const f32x4*)(arow + D3) : (f32x4){0.f, 0.f, 0.f, 0.f};
    f32x4 ps = *(const f32x4*)(psum + (size_t)j * D3 + c4);
    f32x4 eC = *(const f32x4*)(emb + (size_t)RMAX * D3 + c4);
    f32x4 eL = *(const f32x4*)(emb + (size_t)(RMAX - 1) * D3 + c4);
    f32x4 eR = *(const f32x4*)(emb + (size_t)(RMAX + 1) * D3 + c4);
    ushort4 o;
    ushort* op = (ushort*)&o;
#pragma unroll
    for (int k = 0; k < 4; ++k) {
      int d = c4 + k;
      float fC = xc[k] + eC[k];
      float fL = (j > 0)      ? xl[k] + eL[k] : 0.f;
      float fR = (j < MN - 1) ? xr[k] + eR[k] : 0.f;
      float dc = fL * dww[d * 3 + 0] + fC * dww[d * 3 + 1] + fR * dww[d * 3 + 2] + dwb[d];
      op[k] = f2bf(xc[k] + (ps[k] - fC + dc) * (1.f / MN));
    }
    *(ushort4*)(&pes[r][c4]) = o;
  }
  __syncthreads();

  const int wave = tid >> 6, lane = tid & 63;
  const int q15 = lane & 15, quad = lane >> 4;
  const int wrow0 = row0 + wave * 16;

  f32x4 acc[16];
#pragma unroll
  for (int t = 0; t < 16; ++t) acc[t] = (f32x4){0.f, 0.f, 0.f, 0.f};

  const ushort* abase = &pes[wave * 16 + q15][quad * 8];
  const ushort* bbase = (isV ? Wvb : Wkb) + (size_t)q15 * D3 + quad * 8;
#pragma unroll 2
  for (int ks = 0; ks < 6; ++ks) {
    bf16x8 af = ldbf8(abase + ks * 32);
#pragma unroll
    for (int t = 0; t < 16; ++t) {
      bf16x8 bf = ldbf8(bbase + (size_t)t * 16 * D3 + ks * 32);
      acc[t] = __builtin_amdgcn_mfma_f32_16x16x32_bf16(af, bf, acc[t], 0, 0, 0);
    }
  }
#pragma unroll
  for (int reg = 0; reg < 4; ++reg) {
    const int row = wrow0 + quad * 4 + reg;
    const int b_ = row >> 9, s = row & 511;
#pragma unroll
    for (int t = 0; t < 16; ++t) {
      int col = t * 16 + q15;
      float v = acc[t][reg];
      if (isV) {
        int h = t >> 1, dk = (t & 1) * 16 + q15;
        Vt[((size_t)((b_ * NH + h) * DK + dk)) * MN + s] = f2bf(v);
      } else {
        int h = col >> 5, dk = col & 31;
        Kp[((size_t)((b_ * NH + h) * MN + s)) * DK + dk] = f2bf(v);
      }
    }
  }
}

// ---------------------------------------------------------------------------
// MFMA flash attention — R4's proven body (65us, 84 VGPR, 0 conflicts).
// Dual q-tile ILP; head-major Q/Ao; PSTRIDE=36 conflict-free P staging.
// ---------------------------------------------------------------------------
#define PSTRIDE 36  // ushorts per q-row (32 keys + pad)
__global__ __launch_bounds__(256, 3) void attn_mfma_kernel(
    const ushort* __restrict__ Qb, const ushort* __restrict__ Kb,
    const ushort* __restrict__ Vt, ushort* __restrict__ Ao) {
  const int blk = blockIdx.x;
  const int bh = blk & 255;        // low bits -> fixed XCD per (b,h)
  const int qc = blk >> 8;         // 0..7 (128 q rows per block)
  const int h  = bh & 7;
  const int b_ = bh >> 3;
  const int tid = threadIdx.x;
  const int wave = tid >> 6, lane = tid & 63;
  const int q15 = lane & 15, quad = lane >> 4;
  const int q0 = qc * 128 + wave * 32;

  __shared__ ushort Plds[4][2][16][PSTRIDE];   // per-wave, 2 q-tiles
  ushort* prowA = &Plds[wave][0][q15][0];
  ushort* prowB = &Plds[wave][1][q15][0];

  // Q head-major: contiguous 64B rows, adjacent rows share 128B lines
  const ushort* qrow = Qb + ((size_t)((b_ * NH + h) * L) + q0 + q15) * DK + quad * 8;
  const bf16x8 qfA = ldbf8(qrow);
  const bf16x8 qfB = ldbf8(qrow + (size_t)16 * DK);

  f32x4 o0A = {0.f, 0.f, 0.f, 0.f}, o1A = {0.f, 0.f, 0.f, 0.f};
  f32x4 o0B = {0.f, 0.f, 0.f, 0.f}, o1B = {0.f, 0.f, 0.f, 0.f};
  float mA = -1e30f, lA = 0.f, mB = -1e30f, lB = 0.f;
  // softmax in exp2 space: s2 = s * (1/sqrt(32)) * log2(e)
  const float sc2 = 0.17677669529663687f * 1.4426950408889634f;

  const ushort* kbase = Kb + (((size_t)(b_ * NH + h) * MN) + q15) * DK + quad * 8;
  const ushort* vbase = Vt + ((size_t)((b_ * NH + h) * DK) + q15) * MN;

#pragma unroll
  for (int c = 0; c < 4; ++c) {
    const int kb0 = c * 128;
    // prefetch all V fragments for this c-iter (shared by A and B tiles)
    bf16x8 av[8];
#pragma unroll
    for (int g = 0; g < 4; ++g) {
      av[g * 2]     = ldbf8(vbase + (size_t)(kb0 + g * 32 + quad * 8));
      av[g * 2 + 1] = ldbf8(vbase + (size_t)16 * MN + (kb0 + g * 32 + quad * 8));
    }
    f32x4 sA[8], sB[8];
#pragma unroll
    for (int t = 0; t < 8; ++t) {
      bf16x8 af = ldbf8(kbase + (size_t)(kb0 + t * 16) * DK);
      f32x4 z = {0.f, 0.f, 0.f, 0.f};
      sA[t] = __builtin_amdgcn_mfma_f32_16x16x32_bf16(af, qfA, z, 0, 0, 0);
      sB[t] = __builtin_amdgcn_mfma_f32_16x16x32_bf16(af, qfB, z, 0, 0, 0);
    }
    float mlA = -1e30f, mlB = -1e30f;
#pragma unroll
    for (int t = 0; t < 8; ++t)
#pragma unroll
      for (int r = 0; r < 4; ++r) {
        sA[t][r] *= sc2; mlA = fmaxf(mlA, sA[t][r]);
        sB[t][r] *= sc2; mlB = fmaxf(mlB, sB[t][r]);
      }
    mlA = fmaxf(mlA, __shfl_xor(mlA, 16));
    mlB = fmaxf(mlB, __shfl_xor(mlB, 16));
    mlA = fmaxf(mlA, __shfl_xor(mlA, 32));
    mlB = fmaxf(mlB, __shfl_xor(mlB, 32));
    float mnA = fmaxf(mA, mlA), mnB = fmaxf(mB, mlB);
    float aA = fexp2(mA - mnA), aB = fexp2(mB - mnB);
    mA = mnA; mB = mnB;
    lA *= aA; lB *= aB;
#pragma unroll
    for (int r = 0; r < 4; ++r) {
      o0A[r] *= aA; o1A[r] *= aA;
      o0B[r] *= aB; o1B[r] *= aB;
    }
    // per 32-key group: exp2 -> pack(trunc) -> tiny LDS round-trip -> PV mfma
#pragma unroll
    for (int g = 0; g < 4; ++g) {
#pragma unroll
      for (int tp = 0; tp < 2; ++tp) {
        int t = 2 * g + tp;
        float a0 = fexp2(sA[t][0] - mA), a1 = fexp2(sA[t][1] - mA);
        float a2 = fexp2(sA[t][2] - mA), a3 = fexp2(sA[t][3] - mA);
        lA += (a0 + a1) + (a2 + a3);
        uint uA01 = __builtin_amdgcn_perm(__float_as_uint(a1), __float_as_uint(a0), 0x07060302u);
        uint uA23 = __builtin_amdgcn_perm(__float_as_uint(a3), __float_as_uint(a2), 0x07060302u);
        *(uint2*)(prowA + tp * 16 + quad * 4) = make_uint2(uA01, uA23);
        float b0 = fexp2(sB[t][0] - mB), b1 = fexp2(sB[t][1] - mB);
        float b2 = fexp2(sB[t][2] - mB), b3 = fexp2(sB[t][3] - mB);
        lB += (b0 + b1) + (b2 + b3);
        uint uB01 = __builtin_amdgcn_perm(__float_as_uint(b1), __float_as_uint(b0), 0x07060302u);
        uint uB23 = __builtin_amdgcn_perm(__float_as_uint(b3), __float_as_uint(b2), 0x07060302u);
        *(uint2*)(prowB + tp * 16 + quad * 4) = make_uint2(uB01, uB23);
      }
      bf16x8 bfA = ldbf8(prowA + quad * 8);   // B[k=key_local][n=q]
      bf16x8 bfB = ldbf8(prowB + quad * 8);
      o0A = __builtin_amdgcn_mfma_f32_16x16x32_bf16(av[g * 2],     bfA, o0A, 0, 0, 0);
      o1A = __builtin_amdgcn_mfma_f32_16x16x32_bf16(av[g * 2 + 1], bfA, o1A, 0, 0, 0);
      o0B = __builtin_amdgcn_mfma_f32_16x16x32_bf16(av[g * 2],     bfB, o0B, 0, 0, 0);
      o1B = __builtin_amdgcn_mfma_f32_16x16x32_bf16(av[g * 2 + 1], bfB, o1B, 0, 0, 0);
    }
  }
  lA += __shfl_xor(lA, 16); lA += __shfl_xor(lA, 32);
  lB += __shfl_xor(lB, 16); lB += __shfl_xor(lB, 32);
  float rA = 1.f / lA, rB = 1.f / lB;
  // Ao head-major: each 128B line (rows q,q+1) fully written by this wave
  ushort* obA = Ao + ((size_t)((b_ * NH + h) * L) + q0 + q15) * DK + quad * 4;
  *(ushort4*)(obA)      = make_ushort4(f2bf(o0A[0] * rA), f2bf(o0A[1] * rA),
                                       f2bf(o0A[2] * rA), f2bf(o0A[3] * rA));
  *(ushort4*)(obA + 16) = make_ushort4(f2bf(o1A[0] * rA), f2bf(o1A[1] * rA),
                                       f2bf(o1A[2] * rA), f2bf(o1A[3] * rA));
  ushort* obB = obA + (size_t)16 * DK;
  *(ushort4*)(obB)      = make_ushort4(f2bf(o0B[0] * rB), f2bf(o0B[1] * rB),
                                       f2bf(o0B[2] * rB), f2bf(o0B[3] * rB));
  *(ushort4*)(obB + 16) = make_ushort4(f2bf(o1B[0] * rB), f2bf(o1B[1] * rB),
                                       f2bf(o1B[2] * rB), f2bf(o1B[3] * rB));
}

// ---------------------------------------------------------------------------
// Final via MFMA: fc (bf16 MFMA) + Gamma gating + residual + LayerNorm.
// Ao is head-major [b][h][q][dk]; with KS=8, k-chunk ks == head ks,
// so A-loads are abase + ks*L*DK (uniform stride). fcwb unchanged.
// ---------------------------------------------------------------------------
__global__ __launch_bounds__(256, 2) void final_mfma_kernel(
    const ushort* __restrict__ Ao, const ushort* __restrict__ fcwb,
    const float* __restrict__ fcb, const float* __restrict__ G,
    const float* __restrict__ Xs, const float* __restrict__ lnw,
    const float* __restrict__ lnb, float* __restrict__ out) {
  const int tid = threadIdx.x;
  const int wave = tid >> 6, lane = tid & 63;
  const int q15 = lane & 15, quad = lane >> 4;
  const int row0 = blockIdx.x * 64 + wave * 16;
  const int brow = row0 >> 10;            // batch (blocks are 64-row aligned)
  const int srow = (row0 & 1023) + q15;   // q within batch

  f32x4 acc[16];
#pragma unroll
  for (int t = 0; t < 16; ++t) acc[t] = (f32x4){0.f, 0.f, 0.f, 0.f};

  const ushort* abase = Ao + ((size_t)(brow * NH) * L + srow) * DK + quad * 8;
  const ushort* bbase = fcwb + (size_t)q15 * DM + quad * 8;
#pragma unroll 2
  for (int ks = 0; ks < 8; ++ks) {
    bf16x8 af = ldbf8(abase + (size_t)ks * L * DK);
#pragma unroll
    for (int t = 0; t < 16; ++t) {
      bf16x8 bf = ldbf8(bbase + (size_t)t * 16 * DM + ks * 32);
      acc[t] = __builtin_amdgcn_mfma_f32_16x16x32_bf16(af, bf, acc[t], 0, 0, 0);
    }
  }
#pragma unroll
  for (int reg = 0; reg < 4; ++reg) {
    const int grow = row0 + quad * 4 + reg;
    const int b_ = grow >> 10;
    const int gl = (grow & 1023) & 511;
    const float* gbase = G + ((size_t)b_ * MN + gl) * DM + q15;
    const float* xbase = Xs + (size_t)grow * SD + q15;
    float vv[16];
    float s1 = 0.f, s2 = 0.f;
#pragma unroll
    for (int t = 0; t < 16; ++t) {
      int col = t * 16 + q15;
      float fcv = acc[t][reg] + fcb[col];
      float v = xbase[t * 16] + gbase[t * 16] * fcv;
      vv[t] = v; s1 += v; s2 += v * v;
    }
    s1 += __shfl_xor(s1, 1); s2 += __shfl_xor(s2, 1);
    s1 += __shfl_xor(s1, 2); s2 += __shfl_xor(s2, 2);
    s1 += __shfl_xor(s1, 4); s2 += __shfl_xor(s2, 4);
    s1 += __shfl_xor(s1, 8); s2 += __shfl_xor(s2, 8);
    float mu = s1 * (1.f / DM);
    float var = s2 * (1.f / DM) - mu * mu;
    float rs = rsqrtf(var + 1e-5f);
    float* obase = out + (size_t)grow * DM + q15;
#pragma unroll
    for (int t = 0; t < 16; ++t) {
      int col = t * 16 + q15;
      obase[t * 16] = (vv[t] - mu) * rs * lnw[col] + lnb[col];
    }
  }
}

// ---------------------------------------------------------------------------
extern "C" void kernel_launch(void* const* d_in, const int* in_sizes, int n_in,
                              void* d_out, int out_size, void* d_ws, size_t ws_size,
                              hipStream_t stream) {
  const float* x_spatial  = (const float*)d_in[0];
  const float* x_velocity = (const float*)d_in[1];
  const float* Wg   = (const float*)d_in[2];
  const float* w3   = (const float*)d_in[3];
  const float* b3   = (const float*)d_in[4];
  const float* w5   = (const float*)d_in[5];
  const float* b5   = (const float*)d_in[6];
  const float* w7   = (const float*)d_in[7];
  const float* b7   = (const float*)d_in[8];
  const float* remb = (const float*)d_in[9];
  const float* dww  = (const float*)d_in[10];
  const float* dwb  = (const float*)d_in[11];
  const float* Wq   = (const float*)d_in[12];
  const float* Wk   = (const float*)d_in[13];
  const float* Wv   = (const float*)d_in[14];
  const float* fcw  = (const float*)d_in[15];
  const float* fcb  = (const float*)d_in[16];
  const float* lnw  = (const float*)d_in[17];
  const float* lnb  = (const float*)d_in[18];
  float* out = (float*)d_out;

  char* w8 = (char*)d_ws;
  float*  Gamma = (float*)(w8);                     // 16,777,216
  float*  xm    = (float*)(w8 + 16777216);          // 12,582,912
  float*  psum  = (float*)(w8 + 29360128);          //    393,216
  ushort* Qb    = (ushort*)(w8 + 36044800);         // 16,777,216 (bf16, [b][h][q][dk])
  ushort* Kp    = (ushort*)(w8 + 52822016);         //  8,388,608 (bf16, [b][h][s][dk])
  ushort* Vt    = (ushort*)(w8 + 61210624);         //  8,388,608 (bf16, [b][h][dk][s])
  ushort* Ao    = (ushort*)(w8 + 69599232);         // 16,777,216 (bf16, [b][h][q][dk])
  ushort* fcwb  = (ushort*)(w8 + 86376448);         //    131,072 (bf16)
  ushort* Wgb   = (ushort*)(w8 + 105381888);        //     32,768 (bf16)
  ushort* Wqb   = (ushort*)(w8 + 105414656);        //    131,072 (bf16)
  ushort* Wkb   = (ushort*)(w8 + 105545728);        //     98,304 (bf16)
  ushort* Wvb   = (ushort*)(w8 + 105644032);        //     98,304 (bf16)
  // conv im2col scratch lives inside Ao's region (Ao written only later by
  // attn; conv stage finishes before attn runs — same-stream ordering)
  ushort* xvp   = (ushort*)(w8 + 69599232);         //  4,243,456 (bf16 hi+lo)
  ushort* wbigb = (ushort*)(w8 + 69599232 + 4243456); //  172,032 (bf16, [192][448])

  prep_kernel<<<240 + 4144 + 192 + 512, 256, 0, stream>>>(
      Wg, Wgb, Wq, Wqb, Wk, Wkb, Wv, Wvb, fcw, fcwb,
      x_velocity, xvp, w3, w5, w7, wbigb, remb, psum);

  mega1_kernel<<<1280, 256, 0, stream>>>(
      xvp, wbigb, b3, b5, b7, xm,
      x_velocity, Wgb, Gamma, x_spatial, Wqb, Qb);

  projkv_pe_kernel<<<512, 256, 0, stream>>>(
      xm, psum, remb, dww, dwb, Wkb, Wvb, Kp, Vt);

  attn_mfma_kernel<<<B * NH * (L / 128), 256, 0, stream>>>(Qb, Kp, Vt, Ao);
  final_mfma_kernel<<<B * L / 64, 256, 0, stream>>>(Ao, fcwb, fcb, Gamma,
                                                    x_spatial, lnw, lnb, out);
}

// Round 10
// 348.730 us; speedup vs baseline: 1.0011x; 1.0011x over previous
//
#include <hip/hip_runtime.h>

#define B   32
#define L   1024
#define MN  512
#define SD  256
#define VD  64
#define DM  256
#define D3  192
#define NH  8
#define DK  32
#define RMAX 30
#define NREL 61
#define SPAD 518   // MN + 6 (3-zero pad each side) for im2col conv windows

typedef __attribute__((ext_vector_type(8))) __bf16 bf16x8;
typedef __attribute__((ext_vector_type(4))) float  f32x4;

static __device__ __forceinline__ ushort f2bf(float f) {
  unsigned u = __float_as_uint(f);
  unsigned r = (u + 0x7FFFu + ((u >> 16) & 1u)) >> 16;
  return (ushort)r;
}
static __device__ __forceinline__ float bf2f(ushort u) {
  return __uint_as_float((uint)u << 16);
}
static __device__ __forceinline__ bf16x8 ldbf8(const ushort* p) {
  return __builtin_bit_cast(bf16x8, *(const uint4*)p);
}
static __device__ __forceinline__ float fexp2(float x) {
  return __builtin_amdgcn_exp2f(x);
}

// ---------------------------------------------------------------------------
// prep: tobf5 + splitpad + wbig + possum fused (all input-only readers).
// grid = 240 + 4144 + 192 + 512 = 5088 blocks x 256 threads.
// ---------------------------------------------------------------------------
__global__ __launch_bounds__(256) void prep_kernel(
    const float* __restrict__ Wg, ushort* __restrict__ Wgb,
    const float* __restrict__ Wq, ushort* __restrict__ Wqb,
    const float* __restrict__ Wk, ushort* __restrict__ Wkb,
    const float* __restrict__ Wv, ushort* __restrict__ Wvb,
    const float* __restrict__ fcw, ushort* __restrict__ fcwb,
    const float* __restrict__ xv, ushort* __restrict__ xp,
    const float* __restrict__ w3, const float* __restrict__ w5,
    const float* __restrict__ w7, ushort* __restrict__ wb,
    const float* __restrict__ emb, float* __restrict__ psum) {
  int blk = blockIdx.x;
  if (blk < 240) {
    const float* s; ushort* d; int base;
    if (blk < 16)       { s = Wg;  d = Wgb;  base = blk; }
    else if (blk < 80)  { s = Wq;  d = Wqb;  base = blk - 16; }
    else if (blk < 128) { s = Wk;  d = Wkb;  base = blk - 80; }
    else if (blk < 176) { s = Wv;  d = Wvb;  base = blk - 128; }
    else                { s = fcw; d = fcwb; base = blk - 176; }
    int i = (base * 256 + threadIdx.x) * 4;
    float4 v = *(const float4*)(s + i);
    *(ushort4*)(d + i) = make_ushort4(f2bf(v.x), f2bf(v.y), f2bf(v.z), f2bf(v.w));
  } else if (blk < 240 + 4144) {
    int i = (blk - 240) * 256 + threadIdx.x;
    if (i < B * SPAD * VD) {
      int c = i & 63;
      int bp = i >> 6;
      int b_ = bp / SPAD, p = bp - b_ * SPAD;
      int s = p - 3;
      float v = (s >= 0 && s < MN) ? xv[((size_t)b_ * MN + s) * VD + c] : 0.f;
      ushort hi = f2bf(v);
      float vh = __uint_as_float((uint)hi << 16);
      ushort lo = f2bf(v - vh);
      xp[i] = hi;
      xp[(size_t)B * SPAD * VD + i] = lo;
    }
  } else if (blk < 240 + 4144 + 192) {
    const int o = blk - (240 + 4144);     // 0..191
    const int scale = o >> 6, oo = o & 63;
    for (int j = threadIdx.x; j < 448; j += 256) {
      const int k7 = j >> 6, i = j & 63;
      float v = 0.f;
      if (scale == 0) {
        int k = k7 - 2; if (k >= 0 && k < 3) v = w3[((size_t)oo * VD + i) * 3 + k];
      } else if (scale == 1) {
        int k = k7 - 1; if (k >= 0 && k < 5) v = w5[((size_t)oo * VD + i) * 5 + k];
      } else {
        v = w7[((size_t)oo * VD + i) * 7 + k7];
      }
      wb[(size_t)o * 448 + j] = f2bf(v);
    }
  } else {
    const int j = blk - (240 + 4144 + 192);  // 0..511
    const int d = threadIdx.x;
    if (d < D3) {
      float acc = 0.f;
      for (int r = 0; r < NREL; ++r) {
        int v = r - RMAX;
        int cnt;
        if (r == 0)             cnt = max(0, MN - (j + RMAX));
        else if (r == NREL - 1) cnt = max(0, j - RMAX + 1);
        else                    cnt = (j - v >= 0 && j - v < MN) ? 1 : 0;
        acc += (float)cnt * emb[(size_t)r * D3 + d];
      }
      psum[(size_t)j * D3 + d] = acc;
    }
  }
}

// ---------------------------------------------------------------------------
// Shared MFMA projection body: 16 rows/wave, 16 col-tiles, CIN/32 k-steps.
// OMODE: 0 = bf16 Gamma [row][DM] (sigmoid); 4 = bf16 Q head-major.
// R17: Gamma stored bf16 (sigmoid in (0,1), mul-only use) — halves traffic.
// ---------------------------------------------------------------------------
template<int CIN, int OMODE, int ACT, int AF32>
static __device__ __forceinline__ void proj_body(
    int blk, const void* __restrict__ Xv, const ushort* __restrict__ Wb,
    void* __restrict__ Yv, int tid) {
  const int wave = tid >> 6, lane = tid & 63;
  const int q15 = lane & 15, quad = lane >> 4;
  const int row0 = blk * 64 + wave * 16;
  constexpr int KS = CIN / 32;

  f32x4 acc[16];
#pragma unroll
  for (int t = 0; t < 16; ++t) acc[t] = (f32x4){0.f, 0.f, 0.f, 0.f};

  const ushort* abase = (const ushort*)Xv + (size_t)(row0 + q15) * CIN + quad * 8;
  const float*  fbase = (const float*)Xv + (size_t)(row0 + q15) * CIN + quad * 8;
  const ushort* bbase = Wb + (size_t)q15 * CIN + quad * 8;
#pragma unroll 2
  for (int ks = 0; ks < KS; ++ks) {
    bf16x8 af;
    if constexpr (AF32) {
      float4 u0 = *(const float4*)(fbase + ks * 32);
      float4 u1 = *(const float4*)(fbase + ks * 32 + 4);
      uint4 p;
      p.x = (uint)f2bf(u0.x) | ((uint)f2bf(u0.y) << 16);
      p.y = (uint)f2bf(u0.z) | ((uint)f2bf(u0.w) << 16);
      p.z = (uint)f2bf(u1.x) | ((uint)f2bf(u1.y) << 16);
      p.w = (uint)f2bf(u1.z) | ((uint)f2bf(u1.w) << 16);
      af = __builtin_bit_cast(bf16x8, p);
    } else {
      af = ldbf8(abase + ks * 32);
    }
#pragma unroll
    for (int t = 0; t < 16; ++t) {
      bf16x8 bf = ldbf8(bbase + (size_t)t * 16 * CIN + ks * 32);
      acc[t] = __builtin_amdgcn_mfma_f32_16x16x32_bf16(af, bf, acc[t], 0, 0, 0);
    }
  }
#pragma unroll
  for (int reg = 0; reg < 4; ++reg) {
    const int row = row0 + quad * 4 + reg;
#pragma unroll
    for (int t = 0; t < 16; ++t) {
      int col = t * 16 + q15;
      float v = acc[t][reg];
      if (ACT == 1) v = 1.f / (1.f + __expf(-v));
      if (OMODE == 0) {
        ((ushort*)Yv)[(size_t)row * DM + col] = f2bf(v);
      } else {
        int b_ = row >> 10, q = row & 1023;
        int h = col >> 5, dk = col & 31;
        ((ushort*)Yv)[((size_t)((b_ * NH + h) * L + q)) * DK + dk] = f2bf(v);
      }
    }
  }
}

// ---------------------------------------------------------------------------
// R17 proj_gq: Gamma (256) | Q (512) — homogeneous proj_body branches only
// (R16 lesson: conv⊕proj fusion worst-cased regalloc to 64 VGPR -> acc[16]
// spilled -> 90us. Same-profile branches like R15's proj_all are safe).
// ---------------------------------------------------------------------------
__global__ __launch_bounds__(256, 2) void proj_gq_kernel(
    const float* __restrict__ xv, const ushort* __restrict__ Wgb,
    ushort* __restrict__ Gamma,
    const float* __restrict__ xs, const ushort* __restrict__ Wqb,
    ushort* __restrict__ Qb) {
  const int blk = blockIdx.x;
  const int tid = threadIdx.x;
  if (blk < 256) {
    proj_body<VD, 0, 1, 1>(blk, xv, Wgb, Gamma, tid);
  } else {
    proj_body<SD, 4, 0, 1>(blk - 256, xs, Wqb, Qb, tid);
  }
}

// ---------------------------------------------------------------------------
// conv GEMM (standalone again, 16 rows/block, (256,4) proven): 1024 blocks.
// ---------------------------------------------------------------------------
__global__ __launch_bounds__(256, 4) void conv_mfma_kernel(
    const ushort* __restrict__ Xp, const ushort* __restrict__ Wb,
    const float* __restrict__ b3, const float* __restrict__ b5,
    const float* __restrict__ b7, float* __restrict__ xm) {
  const int tid = threadIdx.x;
  const int wave = tid >> 6, lane = tid & 63;
  const int q15 = lane & 15, quad = lane >> 4;
  const int row0 = blockIdx.x * 16;
  const int b_ = row0 >> 9, s0 = row0 & 511;

  f32x4 acc[3];
#pragma unroll
  for (int t = 0; t < 3; ++t) acc[t] = (f32x4){0.f, 0.f, 0.f, 0.f};

  const ushort* hbase = Xp + ((size_t)b_ * SPAD + s0 + q15) * VD + quad * 8;
  const ushort* lbase = hbase + (size_t)B * SPAD * VD;
  const ushort* wbase = Wb + ((size_t)wave * 48 + q15) * 448 + quad * 8;

#pragma unroll 2
  for (int ks = 0; ks < 14; ++ks) {
    bf16x8 ah = ldbf8(hbase + ks * 32);
    bf16x8 al = ldbf8(lbase + ks * 32);
#pragma unroll
    for (int t = 0; t < 3; ++t) {
      bf16x8 bf = ldbf8(wbase + (size_t)t * 16 * 448 + ks * 32);
      acc[t] = __builtin_amdgcn_mfma_f32_16x16x32_bf16(ah, bf, acc[t], 0, 0, 0);
      acc[t] = __builtin_amdgcn_mfma_f32_16x16x32_bf16(al, bf, acc[t], 0, 0, 0);
    }
  }
#pragma unroll
  for (int t = 0; t < 3; ++t) {
    const int col = (wave * 3 + t) * 16 + q15;
    const float bias = col < 64 ? b3[col] : (col < 128 ? b5[col - 64] : b7[col - 128]);
#pragma unroll
    for (int reg = 0; reg < 4; ++reg) {
      const int row = row0 + quad * 4 + reg;
      xm[(size_t)row * D3 + col] = acc[t][reg] + bias;
    }
  }
}

// ---------------------------------------------------------------------------
// projkv_pe: K+V projection with block-local rel-pos-enc into LDS.
// Each block covers 64 rows; 256 threads compute PE for 64x192 elems into
// LDS (bf16, identical f2bf rounding as the old pe4 -> bit-identical A),
// then 4 waves run the 16-row MFMA projection reading A from LDS.
// blk<256: K [b][h][s][dk]; else V^T [b][h][dk][s].
// ---------------------------------------------------------------------------
#define PPAD 200   // LDS row pitch (ushorts): 400B rows, 16B-aligned
__global__ __launch_bounds__(256, 2) void projkv_pe_kernel(
    const float* __restrict__ xm, const float* __restrict__ psum,
    const float* __restrict__ emb, const float* __restrict__ dww,
    const float* __restrict__ dwb, const ushort* __restrict__ Wkb,
    const ushort* __restrict__ Wvb, ushort* __restrict__ Kp,
    ushort* __restrict__ Vt) {
  const int isV = blockIdx.x >> 8;
  const int blk = blockIdx.x & 255;
  const int tid = threadIdx.x;
  const int row0 = blk * 64;

  __shared__ ushort pes[64][PPAD];

  // cooperative PE fill: 64 rows x 192 cols, float4 granularity
#pragma unroll 2
  for (int it = 0; it < 12; ++it) {
    int f = it * 256 + tid;            // 0..3071
    int r = f / 48, c4 = (f % 48) * 4;
    int grow = row0 + r;
    int j = grow & 511;
    const float* arow = xm + (size_t)grow * D3 + c4;
    f32x4 xc = *(const f32x4*)(arow);
    f32x4 xl = (j > 0)      ? *(const f32x4*)(arow - D3) : (f32x4){0.f, 0.f, 0.f, 0.f};
    f32x4 xr = (j < MN - 1) ? *(const f32x4*)(arow + D3) : (f32x4){0.f, 0.f, 0.f, 0.f};
    f32x4 ps = *(const f32x4*)(psum + (size_t)j * D3 + c4);
    f32x4 eC = *(const f32x4*)(emb + (size_t)RMAX * D3 + c4);
    f32x4 eL = *(const f32x4*)(emb + (size_t)(RMAX - 1) * D3 + c4);
    f32x4 eR = *(const f32x4*)(emb + (size_t)(RMAX + 1) * D3 + c4);
    ushort4 o;
    ushort* op = (ushort*)&o;
#pragma unroll
    for (int k = 0; k < 4; ++k) {
      int d = c4 + k;
      float fC = xc[k] + eC[k];
      float fL = (j > 0)      ? xl[k] + eL[k] : 0.f;
      float fR = (j < MN - 1) ? xr[k] + eR[k] : 0.f;
      float dc = fL * dww[d * 3 + 0] + fC * dww[d * 3 + 1] + fR * dww[d * 3 + 2] + dwb[d];
      op[k] = f2bf(xc[k] + (ps[k] - fC + dc) * (1.f / MN));
    }
    *(ushort4*)(&pes[r][c4]) = o;
  }
  __syncthreads();

  const int wave = tid >> 6, lane = tid & 63;
  const int q15 = lane & 15, quad = lane >> 4;
  const int wrow0 = row0 + wave * 16;

  f32x4 acc[16];
#pragma unroll
  for (int t = 0; t < 16; ++t) acc[t] = (f32x4){0.f, 0.f, 0.f, 0.f};

  const ushort* abase = &pes[wave * 16 + q15][quad * 8];
  const ushort* bbase = (isV ? Wvb : Wkb) + (size_t)q15 * D3 + quad * 8;
#pragma unroll 2
  for (int ks = 0; ks < 6; ++ks) {
    bf16x8 af = ldbf8(abase + ks * 32);
#pragma unroll
    for (int t = 0; t < 16; ++t) {
      bf16x8 bf = ldbf8(bbase + (size_t)t * 16 * D3 + ks * 32);
      acc[t] = __builtin_amdgcn_mfma_f32_16x16x32_bf16(af, bf, acc[t], 0, 0, 0);
    }
  }
#pragma unroll
  for (int reg = 0; reg < 4; ++reg) {
    const int row = wrow0 + quad * 4 + reg;
    const int b_ = row >> 9, s = row & 511;
#pragma unroll
    for (int t = 0; t < 16; ++t) {
      int col = t * 16 + q15;
      float v = acc[t][reg];
      if (isV) {
        int h = t >> 1, dk = (t & 1) * 16 + q15;
        Vt[((size_t)((b_ * NH + h) * DK + dk)) * MN + s] = f2bf(v);
      } else {
        int h = col >> 5, dk = col & 31;
        Kp[((size_t)((b_ * NH + h) * MN + s)) * DK + dk] = f2bf(v);
      }
    }
  }
}

// ---------------------------------------------------------------------------
// MFMA flash attention — R4's proven body (65us, 84 VGPR, 0 conflicts).
// Dual q-tile ILP; head-major Q/Ao; PSTRIDE=36 conflict-free P staging.
// ---------------------------------------------------------------------------
#define PSTRIDE 36  // ushorts per q-row (32 keys + pad)
__global__ __launch_bounds__(256, 3) void attn_mfma_kernel(
    const ushort* __restrict__ Qb, const ushort* __restrict__ Kb,
    const ushort* __restrict__ Vt, ushort* __restrict__ Ao) {
  const int blk = blockIdx.x;
  const int bh = blk & 255;        // low bits -> fixed XCD per (b,h)
  const int qc = blk >> 8;         // 0..7 (128 q rows per block)
  const int h  = bh & 7;
  const int b_ = bh >> 3;
  const int tid = threadIdx.x;
  const int wave = tid >> 6, lane = tid & 63;
  const int q15 = lane & 15, quad = lane >> 4;
  const int q0 = qc * 128 + wave * 32;

  __shared__ ushort Plds[4][2][16][PSTRIDE];   // per-wave, 2 q-tiles
  ushort* prowA = &Plds[wave][0][q15][0];
  ushort* prowB = &Plds[wave][1][q15][0];

  // Q head-major: contiguous 64B rows, adjacent rows share 128B lines
  const ushort* qrow = Qb + ((size_t)((b_ * NH + h) * L) + q0 + q15) * DK + quad * 8;
  const bf16x8 qfA = ldbf8(qrow);
  const bf16x8 qfB = ldbf8(qrow + (size_t)16 * DK);

  f32x4 o0A = {0.f, 0.f, 0.f, 0.f}, o1A = {0.f, 0.f, 0.f, 0.f};
  f32x4 o0B = {0.f, 0.f, 0.f, 0.f}, o1B = {0.f, 0.f, 0.f, 0.f};
  float mA = -1e30f, lA = 0.f, mB = -1e30f, lB = 0.f;
  // softmax in exp2 space: s2 = s * (1/sqrt(32)) * log2(e)
  const float sc2 = 0.17677669529663687f * 1.4426950408889634f;

  const ushort* kbase = Kb + (((size_t)(b_ * NH + h) * MN) + q15) * DK + quad * 8;
  const ushort* vbase = Vt + ((size_t)((b_ * NH + h) * DK) + q15) * MN;

#pragma unroll
  for (int c = 0; c < 4; ++c) {
    const int kb0 = c * 128;
    // prefetch all V fragments for this c-iter (shared by A and B tiles)
    bf16x8 av[8];
#pragma unroll
    for (int g = 0; g < 4; ++g) {
      av[g * 2]     = ldbf8(vbase + (size_t)(kb0 + g * 32 + quad * 8));
      av[g * 2 + 1] = ldbf8(vbase + (size_t)16 * MN + (kb0 + g * 32 + quad * 8));
    }
    f32x4 sA[8], sB[8];
#pragma unroll
    for (int t = 0; t < 8; ++t) {
      bf16x8 af = ldbf8(kbase + (size_t)(kb0 + t * 16) * DK);
      f32x4 z = {0.f, 0.f, 0.f, 0.f};
      sA[t] = __builtin_amdgcn_mfma_f32_16x16x32_bf16(af, qfA, z, 0, 0, 0);
      sB[t] = __builtin_amdgcn_mfma_f32_16x16x32_bf16(af, qfB, z, 0, 0, 0);
    }
    float mlA = -1e30f, mlB = -1e30f;
#pragma unroll
    for (int t = 0; t < 8; ++t)
#pragma unroll
      for (int r = 0; r < 4; ++r) {
        sA[t][r] *= sc2; mlA = fmaxf(mlA, sA[t][r]);
        sB[t][r] *= sc2; mlB = fmaxf(mlB, sB[t][r]);
      }
    mlA = fmaxf(mlA, __shfl_xor(mlA, 16));
    mlB = fmaxf(mlB, __shfl_xor(mlB, 16));
    mlA = fmaxf(mlA, __shfl_xor(mlA, 32));
    mlB = fmaxf(mlB, __shfl_xor(mlB, 32));
    float mnA = fmaxf(mA, mlA), mnB = fmaxf(mB, mlB);
    float aA = fexp2(mA - mnA), aB = fexp2(mB - mnB);
    mA = mnA; mB = mnB;
    lA *= aA; lB *= aB;
#pragma unroll
    for (int r = 0; r < 4; ++r) {
      o0A[r] *= aA; o1A[r] *= aA;
      o0B[r] *= aB; o1B[r] *= aB;
    }
    // per 32-key group: exp2 -> pack(trunc) -> tiny LDS round-trip -> PV mfma
#pragma unroll
    for (int g = 0; g < 4; ++g) {
#pragma unroll
      for (int tp = 0; tp < 2; ++tp) {
        int t = 2 * g + tp;
        float a0 = fexp2(sA[t][0] - mA), a1 = fexp2(sA[t][1] - mA);
        float a2 = fexp2(sA[t][2] - mA), a3 = fexp2(sA[t][3] - mA);
        lA += (a0 + a1) + (a2 + a3);
        uint uA01 = __builtin_amdgcn_perm(__float_as_uint(a1), __float_as_uint(a0), 0x07060302u);
        uint uA23 = __builtin_amdgcn_perm(__float_as_uint(a3), __float_as_uint(a2), 0x07060302u);
        *(uint2*)(prowA + tp * 16 + quad * 4) = make_uint2(uA01, uA23);
        float b0 = fexp2(sB[t][0] - mB), b1 = fexp2(sB[t][1] - mB);
        float b2 = fexp2(sB[t][2] - mB), b3 = fexp2(sB[t][3] - mB);
        lB += (b0 + b1) + (b2 + b3);
        uint uB01 = __builtin_amdgcn_perm(__float_as_uint(b1), __float_as_uint(b0), 0x07060302u);
        uint uB23 = __builtin_amdgcn_perm(__float_as_uint(b3), __float_as_uint(b2), 0x07060302u);
        *(uint2*)(prowB + tp * 16 + quad * 4) = make_uint2(uB01, uB23);
      }
      bf16x8 bfA = ldbf8(prowA + quad * 8);   // B[k=key_local][n=q]
      bf16x8 bfB = ldbf8(prowB + quad * 8);
      o0A = __builtin_amdgcn_mfma_f32_16x16x32_bf16(av[g * 2],     bfA, o0A, 0, 0, 0);
      o1A = __builtin_amdgcn_mfma_f32_16x16x32_bf16(av[g * 2 + 1], bfA, o1A, 0, 0, 0);
      o0B = __builtin_amdgcn_mfma_f32_16x16x32_bf16(av[g * 2],     bfB, o0B, 0, 0, 0);
      o1B = __builtin_amdgcn_mfma_f32_16x16x32_bf16(av[g * 2 + 1], bfB, o1B, 0, 0, 0);
    }
  }
  lA += __shfl_xor(lA, 16); lA += __shfl_xor(lA, 32);
  lB += __shfl_xor(lB, 16); lB += __shfl_xor(lB, 32);
  float rA = 1.f / lA, rB = 1.f / lB;
  // Ao head-major: each 128B line (rows q,q+1) fully written by this wave
  ushort* obA = Ao + ((size_t)((b_ * NH + h) * L) + q0 + q15) * DK + quad * 4;
  *(ushort4*)(obA)      = make_ushort4(f2bf(o0A[0] * rA), f2bf(o0A[1] * rA),
                                       f2bf(o0A[2] * rA), f2bf(o0A[3] * rA));
  *(ushort4*)(obA + 16) = make_ushort4(f2bf(o1A[0] * rA), f2bf(o1A[1] * rA),
                                       f2bf(o1A[2] * rA), f2bf(o1A[3] * rA));
  ushort* obB = obA + (size_t)16 * DK;
  *(ushort4*)(obB)      = make_ushort4(f2bf(o0B[0] * rB), f2bf(o0B[1] * rB),
                                       f2bf(o0B[2] * rB), f2bf(o0B[3] * rB));
  *(ushort4*)(obB + 16) = make_ushort4(f2bf(o1B[0] * rB), f2bf(o1B[1] * rB),
                                       f2bf(o1B[2] * rB), f2bf(o1B[3] * rB));
}

// ---------------------------------------------------------------------------
// Final via MFMA: fc (bf16 MFMA) + Gamma gating + residual + LayerNorm.
// Ao is head-major [b][h][q][dk]; k-chunk ks == head ks. Gamma bf16 (R17).
// ---------------------------------------------------------------------------
__global__ __launch_bounds__(256, 2) void final_mfma_kernel(
    const ushort* __restrict__ Ao, const ushort* __restrict__ fcwb,
    const float* __restrict__ fcb, const ushort* __restrict__ G,
    const float* __restrict__ Xs, const float* __restrict__ lnw,
    const float* __restrict__ lnb, float* __restrict__ out) {
  const int tid = threadIdx.x;
  const int wave = tid >> 6, lane = tid & 63;
  const int q15 = lane & 15, quad = lane >> 4;
  const int row0 = blockIdx.x * 64 + wave * 16;
  const int brow = row0 >> 10;            // batch (blocks are 64-row aligned)
  const int srow = (row0 & 1023) + q15;   // q within batch

  f32x4 acc[16];
#pragma unroll
  for (int t = 0; t < 16; ++t) acc[t] = (f32x4){0.f, 0.f, 0.f, 0.f};

  const ushort* abase = Ao + ((size_t)(brow * NH) * L + srow) * DK + quad * 8;
  const ushort* bbase = fcwb + (size_t)q15 * DM + quad * 8;
#pragma unroll 2
  for (int ks = 0; ks < 8; ++ks) {
    bf16x8 af = ldbf8(abase + (size_t)ks * L * DK);
#pragma unroll
    for (int t = 0; t < 16; ++t) {
      bf16x8 bf = ldbf8(bbase + (size_t)t * 16 * DM + ks * 32);
      acc[t] = __builtin_amdgcn_mfma_f32_16x16x32_bf16(af, bf, acc[t], 0, 0, 0);
    }
  }
#pragma unroll
  for (int reg = 0; reg < 4; ++reg) {
    const int grow = row0 + quad * 4 + reg;
    const int b_ = grow >> 10;
    const int gl = (grow & 1023) & 511;
    const ushort* gbase = G + ((size_t)b_ * MN + gl) * DM + q15;
    const float* xbase = Xs + (size_t)grow * SD + q15;
    float vv[16];
    float s1 = 0.f, s2 = 0.f;
#pragma unroll
    for (int t = 0; t < 16; ++t) {
      int col = t * 16 + q15;
      float fcv = acc[t][reg] + fcb[col];
      float v = xbase[t * 16] + bf2f(gbase[t * 16]) * fcv;
      vv[t] = v; s1 += v; s2 += v * v;
    }
    s1 += __shfl_xor(s1, 1); s2 += __shfl_xor(s2, 1);
    s1 += __shfl_xor(s1, 2); s2 += __shfl_xor(s2, 2);
    s1 += __shfl_xor(s1, 4); s2 += __shfl_xor(s2, 4);
    s1 += __shfl_xor(s1, 8); s2 += __shfl_xor(s2, 8);
    float mu = s1 * (1.f / DM);
    float var = s2 * (1.f / DM) - mu * mu;
    float rs = rsqrtf(var + 1e-5f);
    float* obase = out + (size_t)grow * DM + q15;
#pragma unroll
    for (int t = 0; t < 16; ++t) {
      int col = t * 16 + q15;
      obase[t * 16] = (vv[t] - mu) * rs * lnw[col] + lnb[col];
    }
  }
}

// ---------------------------------------------------------------------------
extern "C" void kernel_launch(void* const* d_in, const int* in_sizes, int n_in,
                              void* d_out, int out_size, void* d_ws, size_t ws_size,
                              hipStream_t stream) {
  const float* x_spatial  = (const float*)d_in[0];
  const float* x_velocity = (const float*)d_in[1];
  const float* Wg   = (const float*)d_in[2];
  const float* w3   = (const float*)d_in[3];
  const float* b3   = (const float*)d_in[4];
  const float* w5   = (const float*)d_in[5];
  const float* b5   = (const float*)d_in[6];
  const float* w7   = (const float*)d_in[7];
  const float* b7   = (const float*)d_in[8];
  const float* remb = (const float*)d_in[9];
  const float* dww  = (const float*)d_in[10];
  const float* dwb  = (const float*)d_in[11];
  const float* Wq   = (const float*)d_in[12];
  const float* Wk   = (const float*)d_in[13];
  const float* Wv   = (const float*)d_in[14];
  const float* fcw  = (const float*)d_in[15];
  const float* fcb  = (const float*)d_in[16];
  const float* lnw  = (const float*)d_in[17];
  const float* lnb  = (const float*)d_in[18];
  float* out = (float*)d_out;

  char* w8 = (char*)d_ws;
  ushort* Gamma = (ushort*)(w8);                    //  8,388,608 (bf16, R17)
  float*  xm    = (float*)(w8 + 16777216);          // 12,582,912
  float*  psum  = (float*)(w8 + 29360128);          //    393,216
  ushort* Qb    = (ushort*)(w8 + 36044800);         // 16,777,216 (bf16, [b][h][q][dk])
  ushort* Kp    = (ushort*)(w8 + 52822016);         //  8,388,608 (bf16, [b][h][s][dk])
  ushort* Vt    = (ushort*)(w8 + 61210624);         //  8,388,608 (bf16, [b][h][dk][s])
  ushort* Ao    = (ushort*)(w8 + 69599232);         // 16,777,216 (bf16, [b][h][q][dk])
  ushort* fcwb  = (ushort*)(w8 + 86376448);         //    131,072 (bf16)
  ushort* Wgb   = (ushort*)(w8 + 105381888);        //     32,768 (bf16)
  ushort* Wqb   = (ushort*)(w8 + 105414656);        //    131,072 (bf16)
  ushort* Wkb   = (ushort*)(w8 + 105545728);        //     98,304 (bf16)
  ushort* Wvb   = (ushort*)(w8 + 105644032);        //     98,304 (bf16)
  // conv im2col scratch lives inside Ao's region (Ao written only later by
  // attn; conv stage finishes before attn runs — same-stream ordering)
  ushort* xvp   = (ushort*)(w8 + 69599232);         //  4,243,456 (bf16 hi+lo)
  ushort* wbigb = (ushort*)(w8 + 69599232 + 4243456); //  172,032 (bf16, [192][448])

  prep_kernel<<<240 + 4144 + 192 + 512, 256, 0, stream>>>(
      Wg, Wgb, Wq, Wqb, Wk, Wkb, Wv, Wvb, fcw, fcwb,
      x_velocity, xvp, w3, w5, w7, wbigb, remb, psum);

  conv_mfma_kernel<<<B * MN / 16, 256, 0, stream>>>(xvp, wbigb, b3, b5, b7, xm);

  proj_gq_kernel<<<768, 256, 0, stream>>>(
      x_velocity, Wgb, Gamma, x_spatial, Wqb, Qb);

  projkv_pe_kernel<<<512, 256, 0, stream>>>(
      xm, psum, remb, dww, dwb, Wkb, Wvb, Kp, Vt);

  attn_mfma_kernel<<<B * NH * (L / 128), 256, 0, stream>>>(Qb, Kp, Vt, Ao);
  final_mfma_kernel<<<B * L / 64, 256, 0, stream>>>(Ao, fcwb, fcb, Gamma,
                                                    x_spatial, lnw, lnb, out);
}

// Round 11
// 339.092 us; speedup vs baseline: 1.0296x; 1.0284x over previous
//
#include <hip/hip_runtime.h>

#define B   32
#define L   1024
#define MN  512
#define SD  256
#define VD  64
#define DM  256
#define D3  192
#define NH  8
#define DK  32
#define RMAX 30
#define NREL 61
#define SPAD 518   // MN + 6 (3-zero pad each side) for im2col conv windows

typedef __attribute__((ext_vector_type(8))) __bf16 bf16x8;
typedef __attribute__((ext_vector_type(4))) float  f32x4;

static __device__ __forceinline__ ushort f2bf(float f) {
  unsigned u = __float_as_uint(f);
  unsigned r = (u + 0x7FFFu + ((u >> 16) & 1u)) >> 16;
  return (ushort)r;
}
static __device__ __forceinline__ float bf2f(ushort u) {
  return __uint_as_float((uint)u << 16);
}
static __device__ __forceinline__ bf16x8 ldbf8(const ushort* p) {
  return __builtin_bit_cast(bf16x8, *(const uint4*)p);
}
static __device__ __forceinline__ float fexp2(float x) {
  return __builtin_amdgcn_exp2f(x);
}

// ---------------------------------------------------------------------------
// prep: tobf5 + splitpad + wbig + possum fused (all input-only readers).
// grid = 240 + 4144 + 192 + 512 = 5088 blocks x 256 threads.
// ---------------------------------------------------------------------------
__global__ __launch_bounds__(256) void prep_kernel(
    const float* __restrict__ Wg, ushort* __restrict__ Wgb,
    const float* __restrict__ Wq, ushort* __restrict__ Wqb,
    const float* __restrict__ Wk, ushort* __restrict__ Wkb,
    const float* __restrict__ Wv, ushort* __restrict__ Wvb,
    const float* __restrict__ fcw, ushort* __restrict__ fcwb,
    const float* __restrict__ xv, ushort* __restrict__ xp,
    const float* __restrict__ w3, const float* __restrict__ w5,
    const float* __restrict__ w7, ushort* __restrict__ wb,
    const float* __restrict__ emb, float* __restrict__ psum) {
  int blk = blockIdx.x;
  if (blk < 240) {
    const float* s; ushort* d; int base;
    if (blk < 16)       { s = Wg;  d = Wgb;  base = blk; }
    else if (blk < 80)  { s = Wq;  d = Wqb;  base = blk - 16; }
    else if (blk < 128) { s = Wk;  d = Wkb;  base = blk - 80; }
    else if (blk < 176) { s = Wv;  d = Wvb;  base = blk - 128; }
    else                { s = fcw; d = fcwb; base = blk - 176; }
    int i = (base * 256 + threadIdx.x) * 4;
    float4 v = *(const float4*)(s + i);
    *(ushort4*)(d + i) = make_ushort4(f2bf(v.x), f2bf(v.y), f2bf(v.z), f2bf(v.w));
  } else if (blk < 240 + 4144) {
    int i = (blk - 240) * 256 + threadIdx.x;
    if (i < B * SPAD * VD) {
      int c = i & 63;
      int bp = i >> 6;
      int b_ = bp / SPAD, p = bp - b_ * SPAD;
      int s = p - 3;
      float v = (s >= 0 && s < MN) ? xv[((size_t)b_ * MN + s) * VD + c] : 0.f;
      ushort hi = f2bf(v);
      float vh = __uint_as_float((uint)hi << 16);
      ushort lo = f2bf(v - vh);
      xp[i] = hi;
      xp[(size_t)B * SPAD * VD + i] = lo;
    }
  } else if (blk < 240 + 4144 + 192) {
    const int o = blk - (240 + 4144);     // 0..191
    const int scale = o >> 6, oo = o & 63;
    for (int j = threadIdx.x; j < 448; j += 256) {
      const int k7 = j >> 6, i = j & 63;
      float v = 0.f;
      if (scale == 0) {
        int k = k7 - 2; if (k >= 0 && k < 3) v = w3[((size_t)oo * VD + i) * 3 + k];
      } else if (scale == 1) {
        int k = k7 - 1; if (k >= 0 && k < 5) v = w5[((size_t)oo * VD + i) * 5 + k];
      } else {
        v = w7[((size_t)oo * VD + i) * 7 + k7];
      }
      wb[(size_t)o * 448 + j] = f2bf(v);
    }
  } else {
    const int j = blk - (240 + 4144 + 192);  // 0..511
    const int d = threadIdx.x;
    if (d < D3) {
      float acc = 0.f;
      for (int r = 0; r < NREL; ++r) {
        int v = r - RMAX;
        int cnt;
        if (r == 0)             cnt = max(0, MN - (j + RMAX));
        else if (r == NREL - 1) cnt = max(0, j - RMAX + 1);
        else                    cnt = (j - v >= 0 && j - v < MN) ? 1 : 0;
        acc += (float)cnt * emb[(size_t)r * D3 + d];
      }
      psum[(size_t)j * D3 + d] = acc;
    }
  }
}

// ---------------------------------------------------------------------------
// Shared MFMA projection body: 16 rows/wave, 16 col-tiles, CIN/32 k-steps.
// OMODE: 0 = bf16 Gamma [row][DM] (sigmoid; bf16 store: R17, absmax-verified)
//        2 = bf16 V^T [b][h][dk][s]; 3 = bf16 K [b][h][s][dk];
//        4 = bf16 Q head-major [b][h][q][dk]
// ---------------------------------------------------------------------------
template<int CIN, int OMODE, int ACT, int AF32>
static __device__ __forceinline__ void proj_body(
    int blk, const void* __restrict__ Xv, const ushort* __restrict__ Wb,
    void* __restrict__ Yv, int tid) {
  const int wave = tid >> 6, lane = tid & 63;
  const int q15 = lane & 15, quad = lane >> 4;
  const int row0 = blk * 64 + wave * 16;
  constexpr int KS = CIN / 32;

  f32x4 acc[16];
#pragma unroll
  for (int t = 0; t < 16; ++t) acc[t] = (f32x4){0.f, 0.f, 0.f, 0.f};

  const ushort* abase = (const ushort*)Xv + (size_t)(row0 + q15) * CIN + quad * 8;
  const float*  fbase = (const float*)Xv + (size_t)(row0 + q15) * CIN + quad * 8;
  const ushort* bbase = Wb + (size_t)q15 * CIN + quad * 8;
#pragma unroll 2
  for (int ks = 0; ks < KS; ++ks) {
    bf16x8 af;
    if constexpr (AF32) {
      float4 u0 = *(const float4*)(fbase + ks * 32);
      float4 u1 = *(const float4*)(fbase + ks * 32 + 4);
      uint4 p;
      p.x = (uint)f2bf(u0.x) | ((uint)f2bf(u0.y) << 16);
      p.y = (uint)f2bf(u0.z) | ((uint)f2bf(u0.w) << 16);
      p.z = (uint)f2bf(u1.x) | ((uint)f2bf(u1.y) << 16);
      p.w = (uint)f2bf(u1.z) | ((uint)f2bf(u1.w) << 16);
      af = __builtin_bit_cast(bf16x8, p);
    } else {
      af = ldbf8(abase + ks * 32);
    }
#pragma unroll
    for (int t = 0; t < 16; ++t) {
      bf16x8 bf = ldbf8(bbase + (size_t)t * 16 * CIN + ks * 32);
      acc[t] = __builtin_amdgcn_mfma_f32_16x16x32_bf16(af, bf, acc[t], 0, 0, 0);
    }
  }
#pragma unroll
  for (int reg = 0; reg < 4; ++reg) {
    const int row = row0 + quad * 4 + reg;
#pragma unroll
    for (int t = 0; t < 16; ++t) {
      int col = t * 16 + q15;
      float v = acc[t][reg];
      if (ACT == 1) v = 1.f / (1.f + __expf(-v));
      if (OMODE == 0) {
        ((ushort*)Yv)[(size_t)row * DM + col] = f2bf(v);
      } else if (OMODE == 2) {
        int b_ = row >> 9, s = row & 511;
        int h = t >> 1, dk = (t & 1) * 16 + q15;
        ((ushort*)Yv)[((size_t)((b_ * NH + h) * DK + dk)) * MN + s] = f2bf(v);
      } else if (OMODE == 3) {
        int b_ = row >> 9, s = row & 511;
        int h = col >> 5, dk = col & 31;
        ((ushort*)Yv)[((size_t)((b_ * NH + h) * MN + s)) * DK + dk] = f2bf(v);
      } else {
        int b_ = row >> 10, q = row & 1023;
        int h = col >> 5, dk = col & 31;
        ((ushort*)Yv)[((size_t)((b_ * NH + h) * L + q)) * DK + dk] = f2bf(v);
      }
    }
  }
}

// ---------------------------------------------------------------------------
// proj_all (R15-proven): all four projections in ONE 1280-block launch
// (Gamma 256 | Q 512 | K 256 | V 256). Homogeneous proj_body branches only
// — R16's conv⊕proj mix worst-cased regalloc (64 VGPR, acc spilled, 90us);
// same-profile branches are safe. R18: back to this exact config (337.6us
// proven) after R17's projkv_pe/proj_gq split measured ~11us slower
// (serialized PE-fill + fewer co-scheduled blocks + 8-way LDS conflict).
// ---------------------------------------------------------------------------
__global__ __launch_bounds__(256, 2) void proj_all_kernel(
    const float* __restrict__ xv, const ushort* __restrict__ Wgb,
    ushort* __restrict__ Gamma,
    const float* __restrict__ xs, const ushort* __restrict__ Wqb,
    ushort* __restrict__ Qb,
    const ushort* __restrict__ xpeb, const ushort* __restrict__ Wkb,
    ushort* __restrict__ Kp, const ushort* __restrict__ Wvb,
    ushort* __restrict__ Vt) {
  const int blk = blockIdx.x;
  const int tid = threadIdx.x;
  if (blk < 256) {
    proj_body<VD, 0, 1, 1>(blk, xv, Wgb, Gamma, tid);
  } else if (blk < 768) {
    proj_body<SD, 4, 0, 1>(blk - 256, xs, Wqb, Qb, tid);
  } else if (blk < 1024) {
    proj_body<D3, 3, 0, 0>(blk - 768, xpeb, Wkb, Kp, tid);
  } else {
    proj_body<D3, 2, 0, 0>(blk - 1024, xpeb, Wvb, Vt, tid);
  }
}

// ---------------------------------------------------------------------------
// conv GEMM (standalone, 16 rows/block, (256,4) proven): 1024 blocks.
// ---------------------------------------------------------------------------
__global__ __launch_bounds__(256, 4) void conv_mfma_kernel(
    const ushort* __restrict__ Xp, const ushort* __restrict__ Wb,
    const float* __restrict__ b3, const float* __restrict__ b5,
    const float* __restrict__ b7, float* __restrict__ xm) {
  const int tid = threadIdx.x;
  const int wave = tid >> 6, lane = tid & 63;
  const int q15 = lane & 15, quad = lane >> 4;
  const int row0 = blockIdx.x * 16;
  const int b_ = row0 >> 9, s0 = row0 & 511;

  f32x4 acc[3];
#pragma unroll
  for (int t = 0; t < 3; ++t) acc[t] = (f32x4){0.f, 0.f, 0.f, 0.f};

  const ushort* hbase = Xp + ((size_t)b_ * SPAD + s0 + q15) * VD + quad * 8;
  const ushort* lbase = hbase + (size_t)B * SPAD * VD;
  const ushort* wbase = Wb + ((size_t)wave * 48 + q15) * 448 + quad * 8;

#pragma unroll 2
  for (int ks = 0; ks < 14; ++ks) {
    bf16x8 ah = ldbf8(hbase + ks * 32);
    bf16x8 al = ldbf8(lbase + ks * 32);
#pragma unroll
    for (int t = 0; t < 3; ++t) {
      bf16x8 bf = ldbf8(wbase + (size_t)t * 16 * 448 + ks * 32);
      acc[t] = __builtin_amdgcn_mfma_f32_16x16x32_bf16(ah, bf, acc[t], 0, 0, 0);
      acc[t] = __builtin_amdgcn_mfma_f32_16x16x32_bf16(al, bf, acc[t], 0, 0, 0);
    }
  }
#pragma unroll
  for (int t = 0; t < 3; ++t) {
    const int col = (wave * 3 + t) * 16 + q15;
    const float bias = col < 64 ? b3[col] : (col < 128 ? b5[col - 64] : b7[col - 128]);
#pragma unroll
    for (int reg = 0; reg < 4; ++reg) {
      const int row = row0 + quad * 4 + reg;
      xm[(size_t)row * D3 + col] = acc[t][reg] + bias;
    }
  }
}

// ---------------------------------------------------------------------------
// rel-pos-enc closed form, float4-vectorized (G13), 256-thread flat.
// ---------------------------------------------------------------------------
__global__ __launch_bounds__(256) void pe4_kernel(
    const float* __restrict__ xm, const float* __restrict__ psum,
    const float* __restrict__ emb, const float* __restrict__ dww,
    const float* __restrict__ dwb, ushort* __restrict__ xpe) {
  int i = blockIdx.x * 256 + threadIdx.x;     // B*MN*48 = 786432 units
  int d4 = (i % 48) * 4;
  int bj = i / 48;
  int j = bj & 511;
  const size_t base = (size_t)bj * D3 + d4;
  f32x4 xc = *(const f32x4*)(xm + base);
  f32x4 eC = *(const f32x4*)(emb + (size_t)RMAX * D3 + d4);
  f32x4 eL = *(const f32x4*)(emb + (size_t)(RMAX - 1) * D3 + d4);
  f32x4 eR = *(const f32x4*)(emb + (size_t)(RMAX + 1) * D3 + d4);
  f32x4 ps = *(const f32x4*)(psum + (size_t)j * D3 + d4);
  f32x4 xl = (j > 0)      ? *(const f32x4*)(xm + base - D3) : (f32x4){0.f, 0.f, 0.f, 0.f};
  f32x4 xr = (j < MN - 1) ? *(const f32x4*)(xm + base + D3) : (f32x4){0.f, 0.f, 0.f, 0.f};
  ushort4 o;
  ushort* op = (ushort*)&o;
#pragma unroll
  for (int k = 0; k < 4; ++k) {
    int d = d4 + k;
    float fC = xc[k] + eC[k];
    float fL = (j > 0)      ? xl[k] + eL[k] : 0.f;
    float fR = (j < MN - 1) ? xr[k] + eR[k] : 0.f;
    float dc = fL * dww[d * 3 + 0] + fC * dww[d * 3 + 1] + fR * dww[d * 3 + 2] + dwb[d];
    op[k] = f2bf(xc[k] + (ps[k] - fC + dc) * (1.f / MN));
  }
  *(ushort4*)(xpe + base) = o;
}

// ---------------------------------------------------------------------------
// MFMA flash attention — R4's proven body (65us, 84 VGPR, 0 conflicts).
// Dual q-tile ILP; head-major Q/Ao; PSTRIDE=36 conflict-free P staging.
// ---------------------------------------------------------------------------
#define PSTRIDE 36  // ushorts per q-row (32 keys + pad)
__global__ __launch_bounds__(256, 3) void attn_mfma_kernel(
    const ushort* __restrict__ Qb, const ushort* __restrict__ Kb,
    const ushort* __restrict__ Vt, ushort* __restrict__ Ao) {
  const int blk = blockIdx.x;
  const int bh = blk & 255;        // low bits -> fixed XCD per (b,h)
  const int qc = blk >> 8;         // 0..7 (128 q rows per block)
  const int h  = bh & 7;
  const int b_ = bh >> 3;
  const int tid = threadIdx.x;
  const int wave = tid >> 6, lane = tid & 63;
  const int q15 = lane & 15, quad = lane >> 4;
  const int q0 = qc * 128 + wave * 32;

  __shared__ ushort Plds[4][2][16][PSTRIDE];   // per-wave, 2 q-tiles
  ushort* prowA = &Plds[wave][0][q15][0];
  ushort* prowB = &Plds[wave][1][q15][0];

  // Q head-major: contiguous 64B rows, adjacent rows share 128B lines
  const ushort* qrow = Qb + ((size_t)((b_ * NH + h) * L) + q0 + q15) * DK + quad * 8;
  const bf16x8 qfA = ldbf8(qrow);
  const bf16x8 qfB = ldbf8(qrow + (size_t)16 * DK);

  f32x4 o0A = {0.f, 0.f, 0.f, 0.f}, o1A = {0.f, 0.f, 0.f, 0.f};
  f32x4 o0B = {0.f, 0.f, 0.f, 0.f}, o1B = {0.f, 0.f, 0.f, 0.f};
  float mA = -1e30f, lA = 0.f, mB = -1e30f, lB = 0.f;
  // softmax in exp2 space: s2 = s * (1/sqrt(32)) * log2(e)
  const float sc2 = 0.17677669529663687f * 1.4426950408889634f;

  const ushort* kbase = Kb + (((size_t)(b_ * NH + h) * MN) + q15) * DK + quad * 8;
  const ushort* vbase = Vt + ((size_t)((b_ * NH + h) * DK) + q15) * MN;

#pragma unroll
  for (int c = 0; c < 4; ++c) {
    const int kb0 = c * 128;
    // prefetch all V fragments for this c-iter (shared by A and B tiles)
    bf16x8 av[8];
#pragma unroll
    for (int g = 0; g < 4; ++g) {
      av[g * 2]     = ldbf8(vbase + (size_t)(kb0 + g * 32 + quad * 8));
      av[g * 2 + 1] = ldbf8(vbase + (size_t)16 * MN + (kb0 + g * 32 + quad * 8));
    }
    f32x4 sA[8], sB[8];
#pragma unroll
    for (int t = 0; t < 8; ++t) {
      bf16x8 af = ldbf8(kbase + (size_t)(kb0 + t * 16) * DK);
      f32x4 z = {0.f, 0.f, 0.f, 0.f};
      sA[t] = __builtin_amdgcn_mfma_f32_16x16x32_bf16(af, qfA, z, 0, 0, 0);
      sB[t] = __builtin_amdgcn_mfma_f32_16x16x32_bf16(af, qfB, z, 0, 0, 0);
    }
    float mlA = -1e30f, mlB = -1e30f;
#pragma unroll
    for (int t = 0; t < 8; ++t)
#pragma unroll
      for (int r = 0; r < 4; ++r) {
        sA[t][r] *= sc2; mlA = fmaxf(mlA, sA[t][r]);
        sB[t][r] *= sc2; mlB = fmaxf(mlB, sB[t][r]);
      }
    mlA = fmaxf(mlA, __shfl_xor(mlA, 16));
    mlB = fmaxf(mlB, __shfl_xor(mlB, 16));
    mlA = fmaxf(mlA, __shfl_xor(mlA, 32));
    mlB = fmaxf(mlB, __shfl_xor(mlB, 32));
    float mnA = fmaxf(mA, mlA), mnB = fmaxf(mB, mlB);
    float aA = fexp2(mA - mnA), aB = fexp2(mB - mnB);
    mA = mnA; mB = mnB;
    lA *= aA; lB *= aB;
#pragma unroll
    for (int r = 0; r < 4; ++r) {
      o0A[r] *= aA; o1A[r] *= aA;
      o0B[r] *= aB; o1B[r] *= aB;
    }
    // per 32-key group: exp2 -> pack(trunc) -> tiny LDS round-trip -> PV mfma
#pragma unroll
    for (int g = 0; g < 4; ++g) {
#pragma unroll
      for (int tp = 0; tp < 2; ++tp) {
        int t = 2 * g + tp;
        float a0 = fexp2(sA[t][0] - mA), a1 = fexp2(sA[t][1] - mA);
        float a2 = fexp2(sA[t][2] - mA), a3 = fexp2(sA[t][3] - mA);
        lA += (a0 + a1) + (a2 + a3);
        uint uA01 = __builtin_amdgcn_perm(__float_as_uint(a1), __float_as_uint(a0), 0x07060302u);
        uint uA23 = __builtin_amdgcn_perm(__float_as_uint(a3), __float_as_uint(a2), 0x07060302u);
        *(uint2*)(prowA + tp * 16 + quad * 4) = make_uint2(uA01, uA23);
        float b0 = fexp2(sB[t][0] - mB), b1 = fexp2(sB[t][1] - mB);
        float b2 = fexp2(sB[t][2] - mB), b3 = fexp2(sB[t][3] - mB);
        lB += (b0 + b1) + (b2 + b3);
        uint uB01 = __builtin_amdgcn_perm(__float_as_uint(b1), __float_as_uint(b0), 0x07060302u);
        uint uB23 = __builtin_amdgcn_perm(__float_as_uint(b3), __float_as_uint(b2), 0x07060302u);
        *(uint2*)(prowB + tp * 16 + quad * 4) = make_uint2(uB01, uB23);
      }
      bf16x8 bfA = ldbf8(prowA + quad * 8);   // B[k=key_local][n=q]
      bf16x8 bfB = ldbf8(prowB + quad * 8);
      o0A = __builtin_amdgcn_mfma_f32_16x16x32_bf16(av[g * 2],     bfA, o0A, 0, 0, 0);
      o1A = __builtin_amdgcn_mfma_f32_16x16x32_bf16(av[g * 2 + 1], bfA, o1A, 0, 0, 0);
      o0B = __builtin_amdgcn_mfma_f32_16x16x32_bf16(av[g * 2],     bfB, o0B, 0, 0, 0);
      o1B = __builtin_amdgcn_mfma_f32_16x16x32_bf16(av[g * 2 + 1], bfB, o1B, 0, 0, 0);
    }
  }
  lA += __shfl_xor(lA, 16); lA += __shfl_xor(lA, 32);
  lB += __shfl_xor(lB, 16); lB += __shfl_xor(lB, 32);
  float rA = 1.f / lA, rB = 1.f / lB;
  // Ao head-major: each 128B line (rows q,q+1) fully written by this wave
  ushort* obA = Ao + ((size_t)((b_ * NH + h) * L) + q0 + q15) * DK + quad * 4;
  *(ushort4*)(obA)      = make_ushort4(f2bf(o0A[0] * rA), f2bf(o0A[1] * rA),
                                       f2bf(o0A[2] * rA), f2bf(o0A[3] * rA));
  *(ushort4*)(obA + 16) = make_ushort4(f2bf(o1A[0] * rA), f2bf(o1A[1] * rA),
                                       f2bf(o1A[2] * rA), f2bf(o1A[3] * rA));
  ushort* obB = obA + (size_t)16 * DK;
  *(ushort4*)(obB)      = make_ushort4(f2bf(o0B[0] * rB), f2bf(o0B[1] * rB),
                                       f2bf(o0B[2] * rB), f2bf(o0B[3] * rB));
  *(ushort4*)(obB + 16) = make_ushort4(f2bf(o1B[0] * rB), f2bf(o1B[1] * rB),
                                       f2bf(o1B[2] * rB), f2bf(o1B[3] * rB));
}

// ---------------------------------------------------------------------------
// Final via MFMA: fc (bf16 MFMA) + Gamma gating + residual + LayerNorm.
// Ao is head-major [b][h][q][dk]; k-chunk ks == head ks. Gamma bf16 (R17).
// ---------------------------------------------------------------------------
__global__ __launch_bounds__(256, 2) void final_mfma_kernel(
    const ushort* __restrict__ Ao, const ushort* __restrict__ fcwb,
    const float* __restrict__ fcb, const ushort* __restrict__ G,
    const float* __restrict__ Xs, const float* __restrict__ lnw,
    const float* __restrict__ lnb, float* __restrict__ out) {
  const int tid = threadIdx.x;
  const int wave = tid >> 6, lane = tid & 63;
  const int q15 = lane & 15, quad = lane >> 4;
  const int row0 = blockIdx.x * 64 + wave * 16;
  const int brow = row0 >> 10;            // batch (blocks are 64-row aligned)
  const int srow = (row0 & 1023) + q15;   // q within batch

  f32x4 acc[16];
#pragma unroll
  for (int t = 0; t < 16; ++t) acc[t] = (f32x4){0.f, 0.f, 0.f, 0.f};

  const ushort* abase = Ao + ((size_t)(brow * NH) * L + srow) * DK + quad * 8;
  const ushort* bbase = fcwb + (size_t)q15 * DM + quad * 8;
#pragma unroll 2
  for (int ks = 0; ks < 8; ++ks) {
    bf16x8 af = ldbf8(abase + (size_t)ks * L * DK);
#pragma unroll
    for (int t = 0; t < 16; ++t) {
      bf16x8 bf = ldbf8(bbase + (size_t)t * 16 * DM + ks * 32);
      acc[t] = __builtin_amdgcn_mfma_f32_16x16x32_bf16(af, bf, acc[t], 0, 0, 0);
    }
  }
#pragma unroll
  for (int reg = 0; reg < 4; ++reg) {
    const int grow = row0 + quad * 4 + reg;
    const int b_ = grow >> 10;
    const int gl = (grow & 1023) & 511;
    const ushort* gbase = G + ((size_t)b_ * MN + gl) * DM + q15;
    const float* xbase = Xs + (size_t)grow * SD + q15;
    float vv[16];
    float s1 = 0.f, s2 = 0.f;
#pragma unroll
    for (int t = 0; t < 16; ++t) {
      int col = t * 16 + q15;
      float fcv = acc[t][reg] + fcb[col];
      float v = xbase[t * 16] + bf2f(gbase[t * 16]) * fcv;
      vv[t] = v; s1 += v; s2 += v * v;
    }
    s1 += __shfl_xor(s1, 1); s2 += __shfl_xor(s2, 1);
    s1 += __shfl_xor(s1, 2); s2 += __shfl_xor(s2, 2);
    s1 += __shfl_xor(s1, 4); s2 += __shfl_xor(s2, 4);
    s1 += __shfl_xor(s1, 8); s2 += __shfl_xor(s2, 8);
    float mu = s1 * (1.f / DM);
    float var = s2 * (1.f / DM) - mu * mu;
    float rs = rsqrtf(var + 1e-5f);
    float* obase = out + (size_t)grow * DM + q15;
#pragma unroll
    for (int t = 0; t < 16; ++t) {
      int col = t * 16 + q15;
      obase[t * 16] = (vv[t] - mu) * rs * lnw[col] + lnb[col];
    }
  }
}

// ---------------------------------------------------------------------------
extern "C" void kernel_launch(void* const* d_in, const int* in_sizes, int n_in,
                              void* d_out, int out_size, void* d_ws, size_t ws_size,
                              hipStream_t stream) {
  const float* x_spatial  = (const float*)d_in[0];
  const float* x_velocity = (const float*)d_in[1];
  const float* Wg   = (const float*)d_in[2];
  const float* w3   = (const float*)d_in[3];
  const float* b3   = (const float*)d_in[4];
  const float* w5   = (const float*)d_in[5];
  const float* b5   = (const float*)d_in[6];
  const float* w7   = (const float*)d_in[7];
  const float* b7   = (const float*)d_in[8];
  const float* remb = (const float*)d_in[9];
  const float* dww  = (const float*)d_in[10];
  const float* dwb  = (const float*)d_in[11];
  const float* Wq   = (const float*)d_in[12];
  const float* Wk   = (const float*)d_in[13];
  const float* Wv   = (const float*)d_in[14];
  const float* fcw  = (const float*)d_in[15];
  const float* fcb  = (const float*)d_in[16];
  const float* lnw  = (const float*)d_in[17];
  const float* lnb  = (const float*)d_in[18];
  float* out = (float*)d_out;

  char* w8 = (char*)d_ws;
  ushort* Gamma = (ushort*)(w8);                    //  8,388,608 (bf16, R17)
  float*  xm    = (float*)(w8 + 16777216);          // 12,582,912
  float*  psum  = (float*)(w8 + 29360128);          //    393,216
  ushort* xpeb  = (ushort*)(w8 + 29753344);         //  6,291,456 (bf16)
  ushort* Qb    = (ushort*)(w8 + 36044800);         // 16,777,216 (bf16, [b][h][q][dk])
  ushort* Kp    = (ushort*)(w8 + 52822016);         //  8,388,608 (bf16, [b][h][s][dk])
  ushort* Vt    = (ushort*)(w8 + 61210624);         //  8,388,608 (bf16, [b][h][dk][s])
  ushort* Ao    = (ushort*)(w8 + 69599232);         // 16,777,216 (bf16, [b][h][q][dk])
  ushort* fcwb  = (ushort*)(w8 + 86376448);         //    131,072 (bf16)
  ushort* Wgb   = (ushort*)(w8 + 105381888);        //     32,768 (bf16)
  ushort* Wqb   = (ushort*)(w8 + 105414656);        //    131,072 (bf16)
  ushort* Wkb   = (ushort*)(w8 + 105545728);        //     98,304 (bf16)
  ushort* Wvb   = (ushort*)(w8 + 105644032);        //     98,304 (bf16)
  // conv im2col scratch lives inside Ao's region (Ao written only later by
  // attn; conv stage finishes before attn runs — same-stream ordering)
  ushort* xvp   = (ushort*)(w8 + 69599232);         //  4,243,456 (bf16 hi+lo)
  ushort* wbigb = (ushort*)(w8 + 69599232 + 4243456); //  172,032 (bf16, [192][448])

  prep_kernel<<<240 + 4144 + 192 + 512, 256, 0, stream>>>(
      Wg, Wgb, Wq, Wqb, Wk, Wkb, Wv, Wvb, fcw, fcwb,
      x_velocity, xvp, w3, w5, w7, wbigb, remb, psum);

  conv_mfma_kernel<<<B * MN / 16, 256, 0, stream>>>(xvp, wbigb, b3, b5, b7, xm);
  pe4_kernel<<<(B * MN * 48) / 256, 256, 0, stream>>>(xm, psum, remb, dww, dwb, xpeb);

  proj_all_kernel<<<1280, 256, 0, stream>>>(
      x_velocity, Wgb, Gamma, x_spatial, Wqb, Qb, xpeb, Wkb, Kp, Wvb, Vt);

  attn_mfma_kernel<<<B * NH * (L / 128), 256, 0, stream>>>(Qb, Kp, Vt, Ao);
  final_mfma_kernel<<<B * L / 64, 256, 0, stream>>>(Ao, fcwb, fcb, Gamma,
                                                    x_spatial, lnw, lnb, out);
}

// Round 13
// 316.451 us; speedup vs baseline: 1.1033x; 1.0715x over previous
//
#include <hip/hip_runtime.h>

#define B   32
#define L   1024
#define MN  512
#define SD  256
#define VD  64
#define DM  256
#define D3  192
#define NH  8
#define DK  32
#define RMAX 30
#define NREL 61
#define SPAD 518   // MN + 6 (3-zero pad each side) for im2col conv windows

typedef __attribute__((ext_vector_type(8))) __bf16 bf16x8;
typedef __attribute__((ext_vector_type(4))) float  f32x4;

static __device__ __forceinline__ ushort f2bf(float f) {
  unsigned u = __float_as_uint(f);
  unsigned r = (u + 0x7FFFu + ((u >> 16) & 1u)) >> 16;
  return (ushort)r;
}
static __device__ __forceinline__ float bf2f(ushort u) {
  return __uint_as_float((uint)u << 16);
}
static __device__ __forceinline__ bf16x8 ldbf8(const ushort* p) {
  return __builtin_bit_cast(bf16x8, *(const uint4*)p);
}
static __device__ __forceinline__ float fexp2(float x) {
  return __builtin_amdgcn_exp2f(x);
}
static __device__ __forceinline__ bf16x8 packbf8(const float* fp) {
  uint4 p;
  p.x = (uint)f2bf(fp[0]) | ((uint)f2bf(fp[1]) << 16);
  p.y = (uint)f2bf(fp[2]) | ((uint)f2bf(fp[3]) << 16);
  p.z = (uint)f2bf(fp[4]) | ((uint)f2bf(fp[5]) << 16);
  p.w = (uint)f2bf(fp[6]) | ((uint)f2bf(fp[7]) << 16);
  return __builtin_bit_cast(bf16x8, p);
}

// ---------------------------------------------------------------------------
// prep: tobf5 + splitpad + wbig + possum fused (all input-only readers).
// grid = 240 + 4144 + 192 + 512 = 5088 blocks x 256 threads.
// ---------------------------------------------------------------------------
__global__ __launch_bounds__(256) void prep_kernel(
    const float* __restrict__ Wg, ushort* __restrict__ Wgb,
    const float* __restrict__ Wq, ushort* __restrict__ Wqb,
    const float* __restrict__ Wk, ushort* __restrict__ Wkb,
    const float* __restrict__ Wv, ushort* __restrict__ Wvb,
    const float* __restrict__ fcw, ushort* __restrict__ fcwb,
    const float* __restrict__ xv, ushort* __restrict__ xp,
    const float* __restrict__ w3, const float* __restrict__ w5,
    const float* __restrict__ w7, ushort* __restrict__ wb,
    const float* __restrict__ emb, float* __restrict__ psum) {
  int blk = blockIdx.x;
  if (blk < 240) {
    const float* s; ushort* d; int base;
    if (blk < 16)       { s = Wg;  d = Wgb;  base = blk; }
    else if (blk < 80)  { s = Wq;  d = Wqb;  base = blk - 16; }
    else if (blk < 128) { s = Wk;  d = Wkb;  base = blk - 80; }
    else if (blk < 176) { s = Wv;  d = Wvb;  base = blk - 128; }
    else                { s = fcw; d = fcwb; base = blk - 176; }
    int i = (base * 256 + threadIdx.x) * 4;
    float4 v = *(const float4*)(s + i);
    *(ushort4*)(d + i) = make_ushort4(f2bf(v.x), f2bf(v.y), f2bf(v.z), f2bf(v.w));
  } else if (blk < 240 + 4144) {
    int i = (blk - 240) * 256 + threadIdx.x;
    if (i < B * SPAD * VD) {
      int c = i & 63;
      int bp = i >> 6;
      int b_ = bp / SPAD, p = bp - b_ * SPAD;
      int s = p - 3;
      float v = (s >= 0 && s < MN) ? xv[((size_t)b_ * MN + s) * VD + c] : 0.f;
      ushort hi = f2bf(v);
      float vh = __uint_as_float((uint)hi << 16);
      ushort lo = f2bf(v - vh);
      xp[i] = hi;
      xp[(size_t)B * SPAD * VD + i] = lo;
    }
  } else if (blk < 240 + 4144 + 192) {
    const int o = blk - (240 + 4144);     // 0..191
    const int scale = o >> 6, oo = o & 63;
    for (int j = threadIdx.x; j < 448; j += 256) {
      const int k7 = j >> 6, i = j & 63;
      float v = 0.f;
      if (scale == 0) {
        int k = k7 - 2; if (k >= 0 && k < 3) v = w3[((size_t)oo * VD + i) * 3 + k];
      } else if (scale == 1) {
        int k = k7 - 1; if (k >= 0 && k < 5) v = w5[((size_t)oo * VD + i) * 5 + k];
      } else {
        v = w7[((size_t)oo * VD + i) * 7 + k7];
      }
      wb[(size_t)o * 448 + j] = f2bf(v);
    }
  } else {
    const int j = blk - (240 + 4144 + 192);  // 0..511
    const int d = threadIdx.x;
    if (d < D3) {
      float acc = 0.f;
      for (int r = 0; r < NREL; ++r) {
        int v = r - RMAX;
        int cnt;
        if (r == 0)             cnt = max(0, MN - (j + RMAX));
        else if (r == NREL - 1) cnt = max(0, j - RMAX + 1);
        else                    cnt = (j - v >= 0 && j - v < MN) ? 1 : 0;
        acc += (float)cnt * emb[(size_t)r * D3 + d];
      }
      psum[(size_t)j * D3 + d] = acc;
    }
  }
}

// ---------------------------------------------------------------------------
// R19 dual-row-tile MFMA projection body: wave = 32 rows (2 A-frags sharing
// every B-load — the R0 attn dual-q-tile pattern). Per k-step: 2 A-loads +
// 16 B-loads feed 32 MFMAs (load:MFMA 0.56 vs 1.06 single-tile), and the
// two accumulator chains are independent -> intra-wave ILP hides L2 latency.
// acc = 128 AGPR + ~55 VGPR => launch_bounds(256,1) (allocator law: (256,N)
// targets the 2N-waves/SIMD combined-reg tier; (256,2)=128 would spill).
// OMODE: 0 = bf16 Gamma [row][DM] (sigmoid); 2 = bf16 V^T [b][h][dk][s];
//        3 = bf16 K [b][h][s][dk]; 4 = bf16 Q head-major [b][h][q][dk]
// ---------------------------------------------------------------------------
template<int CIN, int OMODE, int ACT, int AF32>
static __device__ __forceinline__ void proj_body2(
    int blk, const void* __restrict__ Xv, const ushort* __restrict__ Wb,
    void* __restrict__ Yv, int tid) {
  const int wave = tid >> 6, lane = tid & 63;
  const int q15 = lane & 15, quad = lane >> 4;
  const int row0 = blk * 128 + wave * 32;
  constexpr int KS = CIN / 32;

  f32x4 acc0[16], acc1[16];
#pragma unroll
  for (int t = 0; t < 16; ++t) {
    acc0[t] = (f32x4){0.f, 0.f, 0.f, 0.f};
    acc1[t] = (f32x4){0.f, 0.f, 0.f, 0.f};
  }

  const ushort* abase0 = (const ushort*)Xv + (size_t)(row0 + q15) * CIN + quad * 8;
  const ushort* abase1 = abase0 + (size_t)16 * CIN;
  const float*  fbase0 = (const float*)Xv + (size_t)(row0 + q15) * CIN + quad * 8;
  const float*  fbase1 = fbase0 + (size_t)16 * CIN;
  const ushort* bbase = Wb + (size_t)q15 * CIN + quad * 8;
#pragma unroll 2
  for (int ks = 0; ks < KS; ++ks) {
    bf16x8 af0, af1;
    if constexpr (AF32) {
      float f0[8], f1[8];
      *(float4*)(f0)     = *(const float4*)(fbase0 + ks * 32);
      *(float4*)(f0 + 4) = *(const float4*)(fbase0 + ks * 32 + 4);
      *(float4*)(f1)     = *(const float4*)(fbase1 + ks * 32);
      *(float4*)(f1 + 4) = *(const float4*)(fbase1 + ks * 32 + 4);
      af0 = packbf8(f0);
      af1 = packbf8(f1);
    } else {
      af0 = ldbf8(abase0 + ks * 32);
      af1 = ldbf8(abase1 + ks * 32);
    }
#pragma unroll
    for (int t = 0; t < 16; ++t) {
      bf16x8 bf = ldbf8(bbase + (size_t)t * 16 * CIN + ks * 32);
      acc0[t] = __builtin_amdgcn_mfma_f32_16x16x32_bf16(af0, bf, acc0[t], 0, 0, 0);
      acc1[t] = __builtin_amdgcn_mfma_f32_16x16x32_bf16(af1, bf, acc1[t], 0, 0, 0);
    }
  }
#pragma unroll
  for (int p = 0; p < 2; ++p) {
    const int prow0 = row0 + p * 16;
#pragma unroll
    for (int reg = 0; reg < 4; ++reg) {
      const int row = prow0 + quad * 4 + reg;
#pragma unroll
      for (int t = 0; t < 16; ++t) {
        int col = t * 16 + q15;
        float v = (p == 0) ? acc0[t][reg] : acc1[t][reg];
        if (ACT == 1) v = 1.f / (1.f + __expf(-v));
        if (OMODE == 0) {
          ((ushort*)Yv)[(size_t)row * DM + col] = f2bf(v);
        } else if (OMODE == 2) {
          int b_ = row >> 9, s = row & 511;
          int h = t >> 1, dk = (t & 1) * 16 + q15;
          ((ushort*)Yv)[((size_t)((b_ * NH + h) * DK + dk)) * MN + s] = f2bf(v);
        } else if (OMODE == 3) {
          int b_ = row >> 9, s = row & 511;
          int h = col >> 5, dk = col & 31;
          ((ushort*)Yv)[((size_t)((b_ * NH + h) * MN + s)) * DK + dk] = f2bf(v);
        } else {
          int b_ = row >> 10, q = row & 1023;
          int h = col >> 5, dk = col & 31;
          ((ushort*)Yv)[((size_t)((b_ * NH + h) * L + q)) * DK + dk] = f2bf(v);
        }
      }
    }
  }
}

// ---------------------------------------------------------------------------
// proj_all2: four projections, dual-row-tile, one 640-block launch.
// Gamma [0,128) | Q [128,384) | K [384,512) | V [512,640).
// Homogeneous proj branches only (R16 lesson: no conv mixing).
// ---------------------------------------------------------------------------
__global__ __launch_bounds__(256, 1) void proj_all2_kernel(
    const float* __restrict__ xv, const ushort* __restrict__ Wgb,
    ushort* __restrict__ Gamma,
    const float* __restrict__ xs, const ushort* __restrict__ Wqb,
    ushort* __restrict__ Qb,
    const ushort* __restrict__ xpeb, const ushort* __restrict__ Wkb,
    ushort* __restrict__ Kp, const ushort* __restrict__ Wvb,
    ushort* __restrict__ Vt) {
  const int blk = blockIdx.x;
  const int tid = threadIdx.x;
  if (blk < 128) {
    proj_body2<VD, 0, 1, 1>(blk, xv, Wgb, Gamma, tid);
  } else if (blk < 384) {
    proj_body2<SD, 4, 0, 1>(blk - 128, xs, Wqb, Qb, tid);
  } else if (blk < 512) {
    proj_body2<D3, 3, 0, 0>(blk - 384, xpeb, Wkb, Kp, tid);
  } else {
    proj_body2<D3, 2, 0, 0>(blk - 512, xpeb, Wvb, Vt, tid);
  }
}

// ---------------------------------------------------------------------------
// conv GEMM (standalone, 16 rows/block, (256,4) proven): 1024 blocks.
// ---------------------------------------------------------------------------
__global__ __launch_bounds__(256, 4) void conv_mfma_kernel(
    const ushort* __restrict__ Xp, const ushort* __restrict__ Wb,
    const float* __restrict__ b3, const float* __restrict__ b5,
    const float* __restrict__ b7, float* __restrict__ xm) {
  const int tid = threadIdx.x;
  const int wave = tid >> 6, lane = tid & 63;
  const int q15 = lane & 15, quad = lane >> 4;
  const int row0 = blockIdx.x * 16;
  const int b_ = row0 >> 9, s0 = row0 & 511;

  f32x4 acc[3];
#pragma unroll
  for (int t = 0; t < 3; ++t) acc[t] = (f32x4){0.f, 0.f, 0.f, 0.f};

  const ushort* hbase = Xp + ((size_t)b_ * SPAD + s0 + q15) * VD + quad * 8;
  const ushort* lbase = hbase + (size_t)B * SPAD * VD;
  const ushort* wbase = Wb + ((size_t)wave * 48 + q15) * 448 + quad * 8;

#pragma unroll 2
  for (int ks = 0; ks < 14; ++ks) {
    bf16x8 ah = ldbf8(hbase + ks * 32);
    bf16x8 al = ldbf8(lbase + ks * 32);
#pragma unroll
    for (int t = 0; t < 3; ++t) {
      bf16x8 bf = ldbf8(wbase + (size_t)t * 16 * 448 + ks * 32);
      acc[t] = __builtin_amdgcn_mfma_f32_16x16x32_bf16(ah, bf, acc[t], 0, 0, 0);
      acc[t] = __builtin_amdgcn_mfma_f32_16x16x32_bf16(al, bf, acc[t], 0, 0, 0);
    }
  }
#pragma unroll
  for (int t = 0; t < 3; ++t) {
    const int col = (wave * 3 + t) * 16 + q15;
    const float bias = col < 64 ? b3[col] : (col < 128 ? b5[col - 64] : b7[col - 128]);
#pragma unroll
    for (int reg = 0; reg < 4; ++reg) {
      const int row = row0 + quad * 4 + reg;
      xm[(size_t)row * D3 + col] = acc[t][reg] + bias;
    }
  }
}

// ---------------------------------------------------------------------------
// rel-pos-enc closed form, float4-vectorized (G13), 256-thread flat.
// ---------------------------------------------------------------------------
__global__ __launch_bounds__(256) void pe4_kernel(
    const float* __restrict__ xm, const float* __restrict__ psum,
    const float* __restrict__ emb, const float* __restrict__ dww,
    const float* __restrict__ dwb, ushort* __restrict__ xpe) {
  int i = blockIdx.x * 256 + threadIdx.x;     // B*MN*48 = 786432 units
  int d4 = (i % 48) * 4;
  int bj = i / 48;
  int j = bj & 511;
  const size_t base = (size_t)bj * D3 + d4;
  f32x4 xc = *(const f32x4*)(xm + base);
  f32x4 eC = *(const f32x4*)(emb + (size_t)RMAX * D3 + d4);
  f32x4 eL = *(const f32x4*)(emb + (size_t)(RMAX - 1) * D3 + d4);
  f32x4 eR = *(const f32x4*)(emb + (size_t)(RMAX + 1) * D3 + d4);
  f32x4 ps = *(const f32x4*)(psum + (size_t)j * D3 + d4);
  f32x4 xl = (j > 0)      ? *(const f32x4*)(xm + base - D3) : (f32x4){0.f, 0.f, 0.f, 0.f};
  f32x4 xr = (j < MN - 1) ? *(const f32x4*)(xm + base + D3) : (f32x4){0.f, 0.f, 0.f, 0.f};
  ushort4 o;
  ushort* op = (ushort*)&o;
#pragma unroll
  for (int k = 0; k < 4; ++k) {
    int d = d4 + k;
    float fC = xc[k] + eC[k];
    float fL = (j > 0)      ? xl[k] + eL[k] : 0.f;
    float fR = (j < MN - 1) ? xr[k] + eR[k] : 0.f;
    float dc = fL * dww[d * 3 + 0] + fC * dww[d * 3 + 1] + fR * dww[d * 3 + 2] + dwb[d];
    op[k] = f2bf(xc[k] + (ps[k] - fC + dc) * (1.f / MN));
  }
  *(ushort4*)(xpe + base) = o;
}

// ---------------------------------------------------------------------------
// MFMA flash attention — R4's proven body (65us, 84 VGPR, 0 conflicts).
// Dual q-tile ILP; head-major Q/Ao; PSTRIDE=36 conflict-free P staging.
// ---------------------------------------------------------------------------
#define PSTRIDE 36  // ushorts per q-row (32 keys + pad)
__global__ __launch_bounds__(256, 3) void attn_mfma_kernel(
    const ushort* __restrict__ Qb, const ushort* __restrict__ Kb,
    const ushort* __restrict__ Vt, ushort* __restrict__ Ao) {
  const int blk = blockIdx.x;
  const int bh = blk & 255;        // low bits -> fixed XCD per (b,h)
  const int qc = blk >> 8;         // 0..7 (128 q rows per block)
  const int h  = bh & 7;
  const int b_ = bh >> 3;
  const int tid = threadIdx.x;
  const int wave = tid >> 6, lane = tid & 63;
  const int q15 = lane & 15, quad = lane >> 4;
  const int q0 = qc * 128 + wave * 32;

  __shared__ ushort Plds[4][2][16][PSTRIDE];   // per-wave, 2 q-tiles
  ushort* prowA = &Plds[wave][0][q15][0];
  ushort* prowB = &Plds[wave][1][q15][0];

  // Q head-major: contiguous 64B rows, adjacent rows share 128B lines
  const ushort* qrow = Qb + ((size_t)((b_ * NH + h) * L) + q0 + q15) * DK + quad * 8;
  const bf16x8 qfA = ldbf8(qrow);
  const bf16x8 qfB = ldbf8(qrow + (size_t)16 * DK);

  f32x4 o0A = {0.f, 0.f, 0.f, 0.f}, o1A = {0.f, 0.f, 0.f, 0.f};
  f32x4 o0B = {0.f, 0.f, 0.f, 0.f}, o1B = {0.f, 0.f, 0.f, 0.f};
  float mA = -1e30f, lA = 0.f, mB = -1e30f, lB = 0.f;
  // softmax in exp2 space: s2 = s * (1/sqrt(32)) * log2(e)
  const float sc2 = 0.17677669529663687f * 1.4426950408889634f;

  const ushort* kbase = Kb + (((size_t)(b_ * NH + h) * MN) + q15) * DK + quad * 8;
  const ushort* vbase = Vt + ((size_t)((b_ * NH + h) * DK) + q15) * MN;

#pragma unroll
  for (int c = 0; c < 4; ++c) {
    const int kb0 = c * 128;
    // prefetch all V fragments for this c-iter (shared by A and B tiles)
    bf16x8 av[8];
#pragma unroll
    for (int g = 0; g < 4; ++g) {
      av[g * 2]     = ldbf8(vbase + (size_t)(kb0 + g * 32 + quad * 8));
      av[g * 2 + 1] = ldbf8(vbase + (size_t)16 * MN + (kb0 + g * 32 + quad * 8));
    }
    f32x4 sA[8], sB[8];
#pragma unroll
    for (int t = 0; t < 8; ++t) {
      bf16x8 af = ldbf8(kbase + (size_t)(kb0 + t * 16) * DK);
      f32x4 z = {0.f, 0.f, 0.f, 0.f};
      sA[t] = __builtin_amdgcn_mfma_f32_16x16x32_bf16(af, qfA, z, 0, 0, 0);
      sB[t] = __builtin_amdgcn_mfma_f32_16x16x32_bf16(af, qfB, z, 0, 0, 0);
    }
    float mlA = -1e30f, mlB = -1e30f;
#pragma unroll
    for (int t = 0; t < 8; ++t)
#pragma unroll
      for (int r = 0; r < 4; ++r) {
        sA[t][r] *= sc2; mlA = fmaxf(mlA, sA[t][r]);
        sB[t][r] *= sc2; mlB = fmaxf(mlB, sB[t][r]);
      }
    mlA = fmaxf(mlA, __shfl_xor(mlA, 16));
    mlB = fmaxf(mlB, __shfl_xor(mlB, 16));
    mlA = fmaxf(mlA, __shfl_xor(mlA, 32));
    mlB = fmaxf(mlB, __shfl_xor(mlB, 32));
    float mnA = fmaxf(mA, mlA), mnB = fmaxf(mB, mlB);
    float aA = fexp2(mA - mnA), aB = fexp2(mB - mnB);
    mA = mnA; mB = mnB;
    lA *= aA; lB *= aB;
#pragma unroll
    for (int r = 0; r < 4; ++r) {
      o0A[r] *= aA; o1A[r] *= aA;
      o0B[r] *= aB; o1B[r] *= aB;
    }
    // per 32-key group: exp2 -> pack(trunc) -> tiny LDS round-trip -> PV mfma
#pragma unroll
    for (int g = 0; g < 4; ++g) {
#pragma unroll
      for (int tp = 0; tp < 2; ++tp) {
        int t = 2 * g + tp;
        float a0 = fexp2(sA[t][0] - mA), a1 = fexp2(sA[t][1] - mA);
        float a2 = fexp2(sA[t][2] - mA), a3 = fexp2(sA[t][3] - mA);
        lA += (a0 + a1) + (a2 + a3);
        uint uA01 = __builtin_amdgcn_perm(__float_as_uint(a1), __float_as_uint(a0), 0x07060302u);
        uint uA23 = __builtin_amdgcn_perm(__float_as_uint(a3), __float_as_uint(a2), 0x07060302u);
        *(uint2*)(prowA + tp * 16 + quad * 4) = make_uint2(uA01, uA23);
        float b0 = fexp2(sB[t][0] - mB), b1 = fexp2(sB[t][1] - mB);
        float b2 = fexp2(sB[t][2] - mB), b3 = fexp2(sB[t][3] - mB);
        lB += (b0 + b1) + (b2 + b3);
        uint uB01 = __builtin_amdgcn_perm(__float_as_uint(b1), __float_as_uint(b0), 0x07060302u);
        uint uB23 = __builtin_amdgcn_perm(__float_as_uint(b3), __float_as_uint(b2), 0x07060302u);
        *(uint2*)(prowB + tp * 16 + quad * 4) = make_uint2(uB01, uB23);
      }
      bf16x8 bfA = ldbf8(prowA + quad * 8);   // B[k=key_local][n=q]
      bf16x8 bfB = ldbf8(prowB + quad * 8);
      o0A = __builtin_amdgcn_mfma_f32_16x16x32_bf16(av[g * 2],     bfA, o0A, 0, 0, 0);
      o1A = __builtin_amdgcn_mfma_f32_16x16x32_bf16(av[g * 2 + 1], bfA, o1A, 0, 0, 0);
      o0B = __builtin_amdgcn_mfma_f32_16x16x32_bf16(av[g * 2],     bfB, o0B, 0, 0, 0);
      o1B = __builtin_amdgcn_mfma_f32_16x16x32_bf16(av[g * 2 + 1], bfB, o1B, 0, 0, 0);
    }
  }
  lA += __shfl_xor(lA, 16); lA += __shfl_xor(lA, 32);
  lB += __shfl_xor(lB, 16); lB += __shfl_xor(lB, 32);
  float rA = 1.f / lA, rB = 1.f / lB;
  // Ao head-major: each 128B line (rows q,q+1) fully written by this wave
  ushort* obA = Ao + ((size_t)((b_ * NH + h) * L) + q0 + q15) * DK + quad * 4;
  *(ushort4*)(obA)      = make_ushort4(f2bf(o0A[0] * rA), f2bf(o0A[1] * rA),
                                       f2bf(o0A[2] * rA), f2bf(o0A[3] * rA));
  *(ushort4*)(obA + 16) = make_ushort4(f2bf(o1A[0] * rA), f2bf(o1A[1] * rA),
                                       f2bf(o1A[2] * rA), f2bf(o1A[3] * rA));
  ushort* obB = obA + (size_t)16 * DK;
  *(ushort4*)(obB)      = make_ushort4(f2bf(o0B[0] * rB), f2bf(o0B[1] * rB),
                                       f2bf(o0B[2] * rB), f2bf(o0B[3] * rB));
  *(ushort4*)(obB + 16) = make_ushort4(f2bf(o1B[0] * rB), f2bf(o1B[1] * rB),
                                       f2bf(o1B[2] * rB), f2bf(o1B[3] * rB));
}

// ---------------------------------------------------------------------------
// R19 final2: dual-row-tile fc + Gamma gating + residual + LayerNorm.
// Wave = 32 rows (2 A-frags share every fcw B-load); 256 blocks x 128 rows.
// acc = 128 AGPR -> launch_bounds(256,1). Gamma bf16 (R17).
// ---------------------------------------------------------------------------
__global__ __launch_bounds__(256, 1) void final2_mfma_kernel(
    const ushort* __restrict__ Ao, const ushort* __restrict__ fcwb,
    const float* __restrict__ fcb, const ushort* __restrict__ G,
    const float* __restrict__ Xs, const float* __restrict__ lnw,
    const float* __restrict__ lnb, float* __restrict__ out) {
  const int tid = threadIdx.x;
  const int wave = tid >> 6, lane = tid & 63;
  const int q15 = lane & 15, quad = lane >> 4;
  const int row0 = blockIdx.x * 128 + wave * 32;
  const int brow = row0 >> 10;            // batch (128-row blocks stay in-batch)

  f32x4 acc0[16], acc1[16];
#pragma unroll
  for (int t = 0; t < 16; ++t) {
    acc0[t] = (f32x4){0.f, 0.f, 0.f, 0.f};
    acc1[t] = (f32x4){0.f, 0.f, 0.f, 0.f};
  }

  const int srow0 = (row0 & 1023) + q15;
  const ushort* abase0 = Ao + ((size_t)(brow * NH) * L + srow0) * DK + quad * 8;
  const ushort* abase1 = abase0 + (size_t)16 * DK;
  const ushort* bbase = fcwb + (size_t)q15 * DM + quad * 8;
#pragma unroll 2
  for (int ks = 0; ks < 8; ++ks) {
    bf16x8 af0 = ldbf8(abase0 + (size_t)ks * L * DK);
    bf16x8 af1 = ldbf8(abase1 + (size_t)ks * L * DK);
#pragma unroll
    for (int t = 0; t < 16; ++t) {
      bf16x8 bf = ldbf8(bbase + (size_t)t * 16 * DM + ks * 32);
      acc0[t] = __builtin_amdgcn_mfma_f32_16x16x32_bf16(af0, bf, acc0[t], 0, 0, 0);
      acc1[t] = __builtin_amdgcn_mfma_f32_16x16x32_bf16(af1, bf, acc1[t], 0, 0, 0);
    }
  }
#pragma unroll
  for (int p = 0; p < 2; ++p) {
    const int prow0 = row0 + p * 16;
#pragma unroll
    for (int reg = 0; reg < 4; ++reg) {
      const int grow = prow0 + quad * 4 + reg;
      const int b_ = grow >> 10;
      const int gl = (grow & 1023) & 511;
      const ushort* gbase = G + ((size_t)b_ * MN + gl) * DM + q15;
      const float* xbase = Xs + (size_t)grow * SD + q15;
      float vv[16];
      float s1 = 0.f, s2 = 0.f;
#pragma unroll
      for (int t = 0; t < 16; ++t) {
        int col = t * 16 + q15;
        float fcv = ((p == 0) ? acc0[t][reg] : acc1[t][reg]) + fcb[col];
        float v = xbase[t * 16] + bf2f(gbase[t * 16]) * fcv;
        vv[t] = v; s1 += v; s2 += v * v;
      }
      s1 += __shfl_xor(s1, 1); s2 += __shfl_xor(s2, 1);
      s1 += __shfl_xor(s1, 2); s2 += __shfl_xor(s2, 2);
      s1 += __shfl_xor(s1, 4); s2 += __shfl_xor(s2, 4);
      s1 += __shfl_xor(s1, 8); s2 += __shfl_xor(s2, 8);
      float mu = s1 * (1.f / DM);
      float var = s2 * (1.f / DM) - mu * mu;
      float rs = rsqrtf(var + 1e-5f);
      float* obase = out + (size_t)grow * DM + q15;
#pragma unroll
      for (int t = 0; t < 16; ++t) {
        int col = t * 16 + q15;
        obase[t * 16] = (vv[t] - mu) * rs * lnw[col] + lnb[col];
      }
    }
  }
}

// ---------------------------------------------------------------------------
extern "C" void kernel_launch(void* const* d_in, const int* in_sizes, int n_in,
                              void* d_out, int out_size, void* d_ws, size_t ws_size,
                              hipStream_t stream) {
  const float* x_spatial  = (const float*)d_in[0];
  const float* x_velocity = (const float*)d_in[1];
  const float* Wg   = (const float*)d_in[2];
  const float* w3   = (const float*)d_in[3];
  const float* b3   = (const float*)d_in[4];
  const float* w5   = (const float*)d_in[5];
  const float* b5   = (const float*)d_in[6];
  const float* w7   = (const float*)d_in[7];
  const float* b7   = (const float*)d_in[8];
  const float* remb = (const float*)d_in[9];
  const float* dww  = (const float*)d_in[10];
  const float* dwb  = (const float*)d_in[11];
  const float* Wq   = (const float*)d_in[12];
  const float* Wk   = (const float*)d_in[13];
  const float* Wv   = (const float*)d_in[14];
  const float* fcw  = (const float*)d_in[15];
  const float* fcb  = (const float*)d_in[16];
  const float* lnw  = (const float*)d_in[17];
  const float* lnb  = (const float*)d_in[18];
  float* out = (float*)d_out;

  char* w8 = (char*)d_ws;
  ushort* Gamma = (ushort*)(w8);                    //  8,388,608 (bf16, R17)
  float*  xm    = (float*)(w8 + 16777216);          // 12,582,912
  float*  psum  = (float*)(w8 + 29360128);          //    393,216
  ushort* xpeb  = (ushort*)(w8 + 29753344);         //  6,291,456 (bf16)
  ushort* Qb    = (ushort*)(w8 + 36044800);         // 16,777,216 (bf16, [b][h][q][dk])
  ushort* Kp    = (ushort*)(w8 + 52822016);         //  8,388,608 (bf16, [b][h][s][dk])
  ushort* Vt    = (ushort*)(w8 + 61210624);         //  8,388,608 (bf16, [b][h][dk][s])
  ushort* Ao    = (ushort*)(w8 + 69599232);         // 16,777,216 (bf16, [b][h][q][dk])
  ushort* fcwb  = (ushort*)(w8 + 86376448);         //    131,072 (bf16)
  ushort* Wgb   = (ushort*)(w8 + 105381888);        //     32,768 (bf16)
  ushort* Wqb   = (ushort*)(w8 + 105414656);        //    131,072 (bf16)
  ushort* Wkb   = (ushort*)(w8 + 105545728);        //     98,304 (bf16)
  ushort* Wvb   = (ushort*)(w8 + 105644032);        //     98,304 (bf16)
  // conv im2col scratch lives inside Ao's region (Ao written only later by
  // attn; conv stage finishes before attn runs — same-stream ordering)
  ushort* xvp   = (ushort*)(w8 + 69599232);         //  4,243,456 (bf16 hi+lo)
  ushort* wbigb = (ushort*)(w8 + 69599232 + 4243456); //  172,032 (bf16, [192][448])

  prep_kernel<<<240 + 4144 + 192 + 512, 256, 0, stream>>>(
      Wg, Wgb, Wq, Wqb, Wk, Wkb, Wv, Wvb, fcw, fcwb,
      x_velocity, xvp, w3, w5, w7, wbigb, remb, psum);

  conv_mfma_kernel<<<B * MN / 16, 256, 0, stream>>>(xvp, wbigb, b3, b5, b7, xm);
  pe4_kernel<<<(B * MN * 48) / 256, 256, 0, stream>>>(xm, psum, remb, dww, dwb, xpeb);

  proj_all2_kernel<<<640, 256, 0, stream>>>(
      x_velocity, Wgb, Gamma, x_spatial, Wqb, Qb, xpeb, Wkb, Kp, Wvb, Vt);

  attn_mfma_kernel<<<B * NH * (L / 128), 256, 0, stream>>>(Qb, Kp, Vt, Ao);
  final2_mfma_kernel<<<B * L / 128, 256, 0, stream>>>(Ao, fcwb, fcb, Gamma,
                                                      x_spatial, lnw, lnb, out);
}

// Round 14
// 302.175 us; speedup vs baseline: 1.1554x; 1.0472x over previous
//
#include <hip/hip_runtime.h>

#define B   32
#define L   1024
#define MN  512
#define SD  256
#define VD  64
#define DM  256
#define D3  192
#define NH  8
#define DK  32
#define RMAX 30
#define NREL 61
#define SPAD 518   // MN + 6 (3-zero pad each side) for im2col conv windows

typedef __attribute__((ext_vector_type(8))) __bf16 bf16x8;
typedef __attribute__((ext_vector_type(4))) float  f32x4;

static __device__ __forceinline__ ushort f2bf(float f) {
  unsigned u = __float_as_uint(f);
  unsigned r = (u + 0x7FFFu + ((u >> 16) & 1u)) >> 16;
  return (ushort)r;
}
static __device__ __forceinline__ float bf2f(ushort u) {
  return __uint_as_float((uint)u << 16);
}
static __device__ __forceinline__ bf16x8 ldbf8(const ushort* p) {
  return __builtin_bit_cast(bf16x8, *(const uint4*)p);
}
static __device__ __forceinline__ float fexp2(float x) {
  return __builtin_amdgcn_exp2f(x);
}
static __device__ __forceinline__ bf16x8 packbf8(const float* fp) {
  uint4 p;
  p.x = (uint)f2bf(fp[0]) | ((uint)f2bf(fp[1]) << 16);
  p.y = (uint)f2bf(fp[2]) | ((uint)f2bf(fp[3]) << 16);
  p.z = (uint)f2bf(fp[4]) | ((uint)f2bf(fp[5]) << 16);
  p.w = (uint)f2bf(fp[6]) | ((uint)f2bf(fp[7]) << 16);
  return __builtin_bit_cast(bf16x8, p);
}

// ---------------------------------------------------------------------------
// prep: tobf5 + splitpad + wbig + possum fused (all input-only readers).
// grid = 240 + 4144 + 192 + 512 = 5088 blocks x 256 threads.
// ---------------------------------------------------------------------------
__global__ __launch_bounds__(256) void prep_kernel(
    const float* __restrict__ Wg, ushort* __restrict__ Wgb,
    const float* __restrict__ Wq, ushort* __restrict__ Wqb,
    const float* __restrict__ Wk, ushort* __restrict__ Wkb,
    const float* __restrict__ Wv, ushort* __restrict__ Wvb,
    const float* __restrict__ fcw, ushort* __restrict__ fcwb,
    const float* __restrict__ xv, ushort* __restrict__ xp,
    const float* __restrict__ w3, const float* __restrict__ w5,
    const float* __restrict__ w7, ushort* __restrict__ wb,
    const float* __restrict__ emb, float* __restrict__ psum) {
  int blk = blockIdx.x;
  if (blk < 240) {
    const float* s; ushort* d; int base;
    if (blk < 16)       { s = Wg;  d = Wgb;  base = blk; }
    else if (blk < 80)  { s = Wq;  d = Wqb;  base = blk - 16; }
    else if (blk < 128) { s = Wk;  d = Wkb;  base = blk - 80; }
    else if (blk < 176) { s = Wv;  d = Wvb;  base = blk - 128; }
    else                { s = fcw; d = fcwb; base = blk - 176; }
    int i = (base * 256 + threadIdx.x) * 4;
    float4 v = *(const float4*)(s + i);
    *(ushort4*)(d + i) = make_ushort4(f2bf(v.x), f2bf(v.y), f2bf(v.z), f2bf(v.w));
  } else if (blk < 240 + 4144) {
    int i = (blk - 240) * 256 + threadIdx.x;
    if (i < B * SPAD * VD) {
      int c = i & 63;
      int bp = i >> 6;
      int b_ = bp / SPAD, p = bp - b_ * SPAD;
      int s = p - 3;
      float v = (s >= 0 && s < MN) ? xv[((size_t)b_ * MN + s) * VD + c] : 0.f;
      ushort hi = f2bf(v);
      float vh = __uint_as_float((uint)hi << 16);
      ushort lo = f2bf(v - vh);
      xp[i] = hi;
      xp[(size_t)B * SPAD * VD + i] = lo;
    }
  } else if (blk < 240 + 4144 + 192) {
    const int o = blk - (240 + 4144);     // 0..191
    const int scale = o >> 6, oo = o & 63;
    for (int j = threadIdx.x; j < 448; j += 256) {
      const int k7 = j >> 6, i = j & 63;
      float v = 0.f;
      if (scale == 0) {
        int k = k7 - 2; if (k >= 0 && k < 3) v = w3[((size_t)oo * VD + i) * 3 + k];
      } else if (scale == 1) {
        int k = k7 - 1; if (k >= 0 && k < 5) v = w5[((size_t)oo * VD + i) * 5 + k];
      } else {
        v = w7[((size_t)oo * VD + i) * 7 + k7];
      }
      wb[(size_t)o * 448 + j] = f2bf(v);
    }
  } else {
    const int j = blk - (240 + 4144 + 192);  // 0..511
    const int d = threadIdx.x;
    if (d < D3) {
      float acc = 0.f;
      for (int r = 0; r < NREL; ++r) {
        int v = r - RMAX;
        int cnt;
        if (r == 0)             cnt = max(0, MN - (j + RMAX));
        else if (r == NREL - 1) cnt = max(0, j - RMAX + 1);
        else                    cnt = (j - v >= 0 && j - v < MN) ? 1 : 0;
        acc += (float)cnt * emb[(size_t)r * D3 + d];
      }
      psum[(size_t)j * D3 + d] = acc;
    }
  }
}

// ---------------------------------------------------------------------------
// R20 proj body: dual-row-tile (2 A-frags share B-loads, 2 indep chains)
// x half-col-tile (8 of 16 col-tiles per wave). R19 post-mortem: full-16-tile
// dual (184 reg) halved occupancy to ~1 wave/SIMD — ILP gain canceled by TLP
// loss (70.9us ~= 72.5us). Halving acc to 8 tiles (64 acc + ~50 addr ~ 115
// reg) fits the (256,2) 128-reg tier -> 2 waves/SIMD AND keeps the shared
// B-load ILP. Grid x2 (1280) also backfills short Gamma blocks behind Q.
// OMODE: 0 = bf16 Gamma [row][DM] (sigmoid); 2 = bf16 V^T [b][h][dk][s];
//        3 = bf16 K [b][h][s][dk]; 4 = bf16 Q head-major [b][h][q][dk]
// ---------------------------------------------------------------------------
template<int CIN, int OMODE, int ACT, int AF32>
static __device__ __forceinline__ void proj_body3(
    int rowblk, int colh, const void* __restrict__ Xv,
    const ushort* __restrict__ Wb, void* __restrict__ Yv, int tid) {
  const int wave = tid >> 6, lane = tid & 63;
  const int q15 = lane & 15, quad = lane >> 4;
  const int row0 = rowblk * 128 + wave * 32;
  constexpr int KS = CIN / 32;

  f32x4 acc0[8], acc1[8];
#pragma unroll
  for (int t = 0; t < 8; ++t) {
    acc0[t] = (f32x4){0.f, 0.f, 0.f, 0.f};
    acc1[t] = (f32x4){0.f, 0.f, 0.f, 0.f};
  }

  const ushort* abase0 = (const ushort*)Xv + (size_t)(row0 + q15) * CIN + quad * 8;
  const ushort* abase1 = abase0 + (size_t)16 * CIN;
  const float*  fbase0 = (const float*)Xv + (size_t)(row0 + q15) * CIN + quad * 8;
  const float*  fbase1 = fbase0 + (size_t)16 * CIN;
  const ushort* bbase = Wb + (size_t)(colh * 128 + q15) * CIN + quad * 8;
#pragma unroll 2
  for (int ks = 0; ks < KS; ++ks) {
    bf16x8 af0, af1;
    if constexpr (AF32) {
      float f0[8], f1[8];
      *(float4*)(f0)     = *(const float4*)(fbase0 + ks * 32);
      *(float4*)(f0 + 4) = *(const float4*)(fbase0 + ks * 32 + 4);
      *(float4*)(f1)     = *(const float4*)(fbase1 + ks * 32);
      *(float4*)(f1 + 4) = *(const float4*)(fbase1 + ks * 32 + 4);
      af0 = packbf8(f0);
      af1 = packbf8(f1);
    } else {
      af0 = ldbf8(abase0 + ks * 32);
      af1 = ldbf8(abase1 + ks * 32);
    }
#pragma unroll
    for (int t = 0; t < 8; ++t) {
      bf16x8 bf = ldbf8(bbase + (size_t)t * 16 * CIN + ks * 32);
      acc0[t] = __builtin_amdgcn_mfma_f32_16x16x32_bf16(af0, bf, acc0[t], 0, 0, 0);
      acc1[t] = __builtin_amdgcn_mfma_f32_16x16x32_bf16(af1, bf, acc1[t], 0, 0, 0);
    }
  }
#pragma unroll
  for (int p = 0; p < 2; ++p) {
    const int prow0 = row0 + p * 16;
#pragma unroll
    for (int reg = 0; reg < 4; ++reg) {
      const int row = prow0 + quad * 4 + reg;
#pragma unroll
      for (int t = 0; t < 8; ++t) {
        const int tt = colh * 8 + t;
        const int col = tt * 16 + q15;
        float v = (p == 0) ? acc0[t][reg] : acc1[t][reg];
        if (ACT == 1) v = 1.f / (1.f + __expf(-v));
        if (OMODE == 0) {
          ((ushort*)Yv)[(size_t)row * DM + col] = f2bf(v);
        } else if (OMODE == 2) {
          int b_ = row >> 9, s = row & 511;
          int h = tt >> 1, dk = (tt & 1) * 16 + q15;
          ((ushort*)Yv)[((size_t)((b_ * NH + h) * DK + dk)) * MN + s] = f2bf(v);
        } else if (OMODE == 3) {
          int b_ = row >> 9, s = row & 511;
          int h = col >> 5, dk = col & 31;
          ((ushort*)Yv)[((size_t)((b_ * NH + h) * MN + s)) * DK + dk] = f2bf(v);
        } else {
          int b_ = row >> 10, q = row & 1023;
          int h = col >> 5, dk = col & 31;
          ((ushort*)Yv)[((size_t)((b_ * NH + h) * L + q)) * DK + dk] = f2bf(v);
        }
      }
    }
  }
}

// ---------------------------------------------------------------------------
// proj_all3: four projections, dual-row x half-col tiles, 1280 blocks.
// Gamma [0,256) | Q [256,768) | K [768,1024) | V [1024,1280).
// sub = blk-base; rowblk = sub>>1, colh = sub&1.
// ---------------------------------------------------------------------------
__global__ __launch_bounds__(256, 2) void proj_all3_kernel(
    const float* __restrict__ xv, const ushort* __restrict__ Wgb,
    ushort* __restrict__ Gamma,
    const float* __restrict__ xs, const ushort* __restrict__ Wqb,
    ushort* __restrict__ Qb,
    const ushort* __restrict__ xpeb, const ushort* __restrict__ Wkb,
    ushort* __restrict__ Kp, const ushort* __restrict__ Wvb,
    ushort* __restrict__ Vt) {
  const int blk = blockIdx.x;
  const int tid = threadIdx.x;
  if (blk < 256) {
    proj_body3<VD, 0, 1, 1>(blk >> 1, blk & 1, xv, Wgb, Gamma, tid);
  } else if (blk < 768) {
    int sub = blk - 256;
    proj_body3<SD, 4, 0, 1>(sub >> 1, sub & 1, xs, Wqb, Qb, tid);
  } else if (blk < 1024) {
    int sub = blk - 768;
    proj_body3<D3, 3, 0, 0>(sub >> 1, sub & 1, xpeb, Wkb, Kp, tid);
  } else {
    int sub = blk - 1024;
    proj_body3<D3, 2, 0, 0>(sub >> 1, sub & 1, xpeb, Wvb, Vt, tid);
  }
}

// ---------------------------------------------------------------------------
// conv GEMM (standalone, 16 rows/block, (256,4) proven): 1024 blocks.
// ---------------------------------------------------------------------------
__global__ __launch_bounds__(256, 4) void conv_mfma_kernel(
    const ushort* __restrict__ Xp, const ushort* __restrict__ Wb,
    const float* __restrict__ b3, const float* __restrict__ b5,
    const float* __restrict__ b7, float* __restrict__ xm) {
  const int tid = threadIdx.x;
  const int wave = tid >> 6, lane = tid & 63;
  const int q15 = lane & 15, quad = lane >> 4;
  const int row0 = blockIdx.x * 16;
  const int b_ = row0 >> 9, s0 = row0 & 511;

  f32x4 acc[3];
#pragma unroll
  for (int t = 0; t < 3; ++t) acc[t] = (f32x4){0.f, 0.f, 0.f, 0.f};

  const ushort* hbase = Xp + ((size_t)b_ * SPAD + s0 + q15) * VD + quad * 8;
  const ushort* lbase = hbase + (size_t)B * SPAD * VD;
  const ushort* wbase = Wb + ((size_t)wave * 48 + q15) * 448 + quad * 8;

#pragma unroll 2
  for (int ks = 0; ks < 14; ++ks) {
    bf16x8 ah = ldbf8(hbase + ks * 32);
    bf16x8 al = ldbf8(lbase + ks * 32);
#pragma unroll
    for (int t = 0; t < 3; ++t) {
      bf16x8 bf = ldbf8(wbase + (size_t)t * 16 * 448 + ks * 32);
      acc[t] = __builtin_amdgcn_mfma_f32_16x16x32_bf16(ah, bf, acc[t], 0, 0, 0);
      acc[t] = __builtin_amdgcn_mfma_f32_16x16x32_bf16(al, bf, acc[t], 0, 0, 0);
    }
  }
#pragma unroll
  for (int t = 0; t < 3; ++t) {
    const int col = (wave * 3 + t) * 16 + q15;
    const float bias = col < 64 ? b3[col] : (col < 128 ? b5[col - 64] : b7[col - 128]);
#pragma unroll
    for (int reg = 0; reg < 4; ++reg) {
      const int row = row0 + quad * 4 + reg;
      xm[(size_t)row * D3 + col] = acc[t][reg] + bias;
    }
  }
}

// ---------------------------------------------------------------------------
// rel-pos-enc closed form, float4-vectorized (G13), 256-thread flat.
// ---------------------------------------------------------------------------
__global__ __launch_bounds__(256) void pe4_kernel(
    const float* __restrict__ xm, const float* __restrict__ psum,
    const float* __restrict__ emb, const float* __restrict__ dww,
    const float* __restrict__ dwb, ushort* __restrict__ xpe) {
  int i = blockIdx.x * 256 + threadIdx.x;     // B*MN*48 = 786432 units
  int d4 = (i % 48) * 4;
  int bj = i / 48;
  int j = bj & 511;
  const size_t base = (size_t)bj * D3 + d4;
  f32x4 xc = *(const f32x4*)(xm + base);
  f32x4 eC = *(const f32x4*)(emb + (size_t)RMAX * D3 + d4);
  f32x4 eL = *(const f32x4*)(emb + (size_t)(RMAX - 1) * D3 + d4);
  f32x4 eR = *(const f32x4*)(emb + (size_t)(RMAX + 1) * D3 + d4);
  f32x4 ps = *(const f32x4*)(psum + (size_t)j * D3 + d4);
  f32x4 xl = (j > 0)      ? *(const f32x4*)(xm + base - D3) : (f32x4){0.f, 0.f, 0.f, 0.f};
  f32x4 xr = (j < MN - 1) ? *(const f32x4*)(xm + base + D3) : (f32x4){0.f, 0.f, 0.f, 0.f};
  ushort4 o;
  ushort* op = (ushort*)&o;
#pragma unroll
  for (int k = 0; k < 4; ++k) {
    int d = d4 + k;
    float fC = xc[k] + eC[k];
    float fL = (j > 0)      ? xl[k] + eL[k] : 0.f;
    float fR = (j < MN - 1) ? xr[k] + eR[k] : 0.f;
    float dc = fL * dww[d * 3 + 0] + fC * dww[d * 3 + 1] + fR * dww[d * 3 + 2] + dwb[d];
    op[k] = f2bf(xc[k] + (ps[k] - fC + dc) * (1.f / MN));
  }
  *(ushort4*)(xpe + base) = o;
}

// ---------------------------------------------------------------------------
// MFMA flash attention — R4's proven body (65us, 84 VGPR, 0 conflicts).
// Dual q-tile ILP; head-major Q/Ao; PSTRIDE=36 conflict-free P staging.
// ---------------------------------------------------------------------------
#define PSTRIDE 36  // ushorts per q-row (32 keys + pad)
__global__ __launch_bounds__(256, 3) void attn_mfma_kernel(
    const ushort* __restrict__ Qb, const ushort* __restrict__ Kb,
    const ushort* __restrict__ Vt, ushort* __restrict__ Ao) {
  const int blk = blockIdx.x;
  const int bh = blk & 255;        // low bits -> fixed XCD per (b,h)
  const int qc = blk >> 8;         // 0..7 (128 q rows per block)
  const int h  = bh & 7;
  const int b_ = bh >> 3;
  const int tid = threadIdx.x;
  const int wave = tid >> 6, lane = tid & 63;
  const int q15 = lane & 15, quad = lane >> 4;
  const int q0 = qc * 128 + wave * 32;

  __shared__ ushort Plds[4][2][16][PSTRIDE];   // per-wave, 2 q-tiles
  ushort* prowA = &Plds[wave][0][q15][0];
  ushort* prowB = &Plds[wave][1][q15][0];

  // Q head-major: contiguous 64B rows, adjacent rows share 128B lines
  const ushort* qrow = Qb + ((size_t)((b_ * NH + h) * L) + q0 + q15) * DK + quad * 8;
  const bf16x8 qfA = ldbf8(qrow);
  const bf16x8 qfB = ldbf8(qrow + (size_t)16 * DK);

  f32x4 o0A = {0.f, 0.f, 0.f, 0.f}, o1A = {0.f, 0.f, 0.f, 0.f};
  f32x4 o0B = {0.f, 0.f, 0.f, 0.f}, o1B = {0.f, 0.f, 0.f, 0.f};
  float mA = -1e30f, lA = 0.f, mB = -1e30f, lB = 0.f;
  // softmax in exp2 space: s2 = s * (1/sqrt(32)) * log2(e)
  const float sc2 = 0.17677669529663687f * 1.4426950408889634f;

  const ushort* kbase = Kb + (((size_t)(b_ * NH + h) * MN) + q15) * DK + quad * 8;
  const ushort* vbase = Vt + ((size_t)((b_ * NH + h) * DK) + q15) * MN;

#pragma unroll
  for (int c = 0; c < 4; ++c) {
    const int kb0 = c * 128;
    // prefetch all V fragments for this c-iter (shared by A and B tiles)
    bf16x8 av[8];
#pragma unroll
    for (int g = 0; g < 4; ++g) {
      av[g * 2]     = ldbf8(vbase + (size_t)(kb0 + g * 32 + quad * 8));
      av[g * 2 + 1] = ldbf8(vbase + (size_t)16 * MN + (kb0 + g * 32 + quad * 8));
    }
    f32x4 sA[8], sB[8];
#pragma unroll
    for (int t = 0; t < 8; ++t) {
      bf16x8 af = ldbf8(kbase + (size_t)(kb0 + t * 16) * DK);
      f32x4 z = {0.f, 0.f, 0.f, 0.f};
      sA[t] = __builtin_amdgcn_mfma_f32_16x16x32_bf16(af, qfA, z, 0, 0, 0);
      sB[t] = __builtin_amdgcn_mfma_f32_16x16x32_bf16(af, qfB, z, 0, 0, 0);
    }
    float mlA = -1e30f, mlB = -1e30f;
#pragma unroll
    for (int t = 0; t < 8; ++t)
#pragma unroll
      for (int r = 0; r < 4; ++r) {
        sA[t][r] *= sc2; mlA = fmaxf(mlA, sA[t][r]);
        sB[t][r] *= sc2; mlB = fmaxf(mlB, sB[t][r]);
      }
    mlA = fmaxf(mlA, __shfl_xor(mlA, 16));
    mlB = fmaxf(mlB, __shfl_xor(mlB, 16));
    mlA = fmaxf(mlA, __shfl_xor(mlA, 32));
    mlB = fmaxf(mlB, __shfl_xor(mlB, 32));
    float mnA = fmaxf(mA, mlA), mnB = fmaxf(mB, mlB);
    float aA = fexp2(mA - mnA), aB = fexp2(mB - mnB);
    mA = mnA; mB = mnB;
    lA *= aA; lB *= aB;
#pragma unroll
    for (int r = 0; r < 4; ++r) {
      o0A[r] *= aA; o1A[r] *= aA;
      o0B[r] *= aB; o1B[r] *= aB;
    }
    // per 32-key group: exp2 -> pack(trunc) -> tiny LDS round-trip -> PV mfma
#pragma unroll
    for (int g = 0; g < 4; ++g) {
#pragma unroll
      for (int tp = 0; tp < 2; ++tp) {
        int t = 2 * g + tp;
        float a0 = fexp2(sA[t][0] - mA), a1 = fexp2(sA[t][1] - mA);
        float a2 = fexp2(sA[t][2] - mA), a3 = fexp2(sA[t][3] - mA);
        lA += (a0 + a1) + (a2 + a3);
        uint uA01 = __builtin_amdgcn_perm(__float_as_uint(a1), __float_as_uint(a0), 0x07060302u);
        uint uA23 = __builtin_amdgcn_perm(__float_as_uint(a3), __float_as_uint(a2), 0x07060302u);
        *(uint2*)(prowA + tp * 16 + quad * 4) = make_uint2(uA01, uA23);
        float b0 = fexp2(sB[t][0] - mB), b1 = fexp2(sB[t][1] - mB);
        float b2 = fexp2(sB[t][2] - mB), b3 = fexp2(sB[t][3] - mB);
        lB += (b0 + b1) + (b2 + b3);
        uint uB01 = __builtin_amdgcn_perm(__float_as_uint(b1), __float_as_uint(b0), 0x07060302u);
        uint uB23 = __builtin_amdgcn_perm(__float_as_uint(b3), __float_as_uint(b2), 0x07060302u);
        *(uint2*)(prowB + tp * 16 + quad * 4) = make_uint2(uB01, uB23);
      }
      bf16x8 bfA = ldbf8(prowA + quad * 8);   // B[k=key_local][n=q]
      bf16x8 bfB = ldbf8(prowB + quad * 8);
      o0A = __builtin_amdgcn_mfma_f32_16x16x32_bf16(av[g * 2],     bfA, o0A, 0, 0, 0);
      o1A = __builtin_amdgcn_mfma_f32_16x16x32_bf16(av[g * 2 + 1], bfA, o1A, 0, 0, 0);
      o0B = __builtin_amdgcn_mfma_f32_16x16x32_bf16(av[g * 2],     bfB, o0B, 0, 0, 0);
      o1B = __builtin_amdgcn_mfma_f32_16x16x32_bf16(av[g * 2 + 1], bfB, o1B, 0, 0, 0);
    }
  }
  lA += __shfl_xor(lA, 16); lA += __shfl_xor(lA, 32);
  lB += __shfl_xor(lB, 16); lB += __shfl_xor(lB, 32);
  float rA = 1.f / lA, rB = 1.f / lB;
  // Ao head-major: each 128B line (rows q,q+1) fully written by this wave
  ushort* obA = Ao + ((size_t)((b_ * NH + h) * L) + q0 + q15) * DK + quad * 4;
  *(ushort4*)(obA)      = make_ushort4(f2bf(o0A[0] * rA), f2bf(o0A[1] * rA),
                                       f2bf(o0A[2] * rA), f2bf(o0A[3] * rA));
  *(ushort4*)(obA + 16) = make_ushort4(f2bf(o1A[0] * rA), f2bf(o1A[1] * rA),
                                       f2bf(o1A[2] * rA), f2bf(o1A[3] * rA));
  ushort* obB = obA + (size_t)16 * DK;
  *(ushort4*)(obB)      = make_ushort4(f2bf(o0B[0] * rB), f2bf(o0B[1] * rB),
                                       f2bf(o0B[2] * rB), f2bf(o0B[3] * rB));
  *(ushort4*)(obB + 16) = make_ushort4(f2bf(o1B[0] * rB), f2bf(o1B[1] * rB),
                                       f2bf(o1B[2] * rB), f2bf(o1B[3] * rB));
}

// ---------------------------------------------------------------------------
// final2: dual-row-tile fc + Gamma gating + residual + LayerNorm (R19 win).
// Wave = 32 rows (2 A-frags share every fcw B-load); 256 blocks x 128 rows.
// acc = 128 AGPR -> launch_bounds(256,1). Gamma bf16 (R17).
// ---------------------------------------------------------------------------
__global__ __launch_bounds__(256, 1) void final2_mfma_kernel(
    const ushort* __restrict__ Ao, const ushort* __restrict__ fcwb,
    const float* __restrict__ fcb, const ushort* __restrict__ G,
    const float* __restrict__ Xs, const float* __restrict__ lnw,
    const float* __restrict__ lnb, float* __restrict__ out) {
  const int tid = threadIdx.x;
  const int wave = tid >> 6, lane = tid & 63;
  const int q15 = lane & 15, quad = lane >> 4;
  const int row0 = blockIdx.x * 128 + wave * 32;
  const int brow = row0 >> 10;            // batch (128-row blocks stay in-batch)

  f32x4 acc0[16], acc1[16];
#pragma unroll
  for (int t = 0; t < 16; ++t) {
    acc0[t] = (f32x4){0.f, 0.f, 0.f, 0.f};
    acc1[t] = (f32x4){0.f, 0.f, 0.f, 0.f};
  }

  const int srow0 = (row0 & 1023) + q15;
  const ushort* abase0 = Ao + ((size_t)(brow * NH) * L + srow0) * DK + quad * 8;
  const ushort* abase1 = abase0 + (size_t)16 * DK;
  const ushort* bbase = fcwb + (size_t)q15 * DM + quad * 8;
#pragma unroll 2
  for (int ks = 0; ks < 8; ++ks) {
    bf16x8 af0 = ldbf8(abase0 + (size_t)ks * L * DK);
    bf16x8 af1 = ldbf8(abase1 + (size_t)ks * L * DK);
#pragma unroll
    for (int t = 0; t < 16; ++t) {
      bf16x8 bf = ldbf8(bbase + (size_t)t * 16 * DM + ks * 32);
      acc0[t] = __builtin_amdgcn_mfma_f32_16x16x32_bf16(af0, bf, acc0[t], 0, 0, 0);
      acc1[t] = __builtin_amdgcn_mfma_f32_16x16x32_bf16(af1, bf, acc1[t], 0, 0, 0);
    }
  }
#pragma unroll
  for (int p = 0; p < 2; ++p) {
    const int prow0 = row0 + p * 16;
#pragma unroll
    for (int reg = 0; reg < 4; ++reg) {
      const int grow = prow0 + quad * 4 + reg;
      const int b_ = grow >> 10;
      const int gl = (grow & 1023) & 511;
      const ushort* gbase = G + ((size_t)b_ * MN + gl) * DM + q15;
      const float* xbase = Xs + (size_t)grow * SD + q15;
      float vv[16];
      float s1 = 0.f, s2 = 0.f;
#pragma unroll
      for (int t = 0; t < 16; ++t) {
        int col = t * 16 + q15;
        float fcv = ((p == 0) ? acc0[t][reg] : acc1[t][reg]) + fcb[col];
        float v = xbase[t * 16] + bf2f(gbase[t * 16]) * fcv;
        vv[t] = v; s1 += v; s2 += v * v;
      }
      s1 += __shfl_xor(s1, 1); s2 += __shfl_xor(s2, 1);
      s1 += __shfl_xor(s1, 2); s2 += __shfl_xor(s2, 2);
      s1 += __shfl_xor(s1, 4); s2 += __shfl_xor(s2, 4);
      s1 += __shfl_xor(s1, 8); s2 += __shfl_xor(s2, 8);
      float mu = s1 * (1.f / DM);
      float var = s2 * (1.f / DM) - mu * mu;
      float rs = rsqrtf(var + 1e-5f);
      float* obase = out + (size_t)grow * DM + q15;
#pragma unroll
      for (int t = 0; t < 16; ++t) {
        int col = t * 16 + q15;
        obase[t * 16] = (vv[t] - mu) * rs * lnw[col] + lnb[col];
      }
    }
  }
}

// ---------------------------------------------------------------------------
extern "C" void kernel_launch(void* const* d_in, const int* in_sizes, int n_in,
                              void* d_out, int out_size, void* d_ws, size_t ws_size,
                              hipStream_t stream) {
  const float* x_spatial  = (const float*)d_in[0];
  const float* x_velocity = (const float*)d_in[1];
  const float* Wg   = (const float*)d_in[2];
  const float* w3   = (const float*)d_in[3];
  const float* b3   = (const float*)d_in[4];
  const float* w5   = (const float*)d_in[5];
  const float* b5   = (const float*)d_in[6];
  const float* w7   = (const float*)d_in[7];
  const float* b7   = (const float*)d_in[8];
  const float* remb = (const float*)d_in[9];
  const float* dww  = (const float*)d_in[10];
  const float* dwb  = (const float*)d_in[11];
  const float* Wq   = (const float*)d_in[12];
  const float* Wk   = (const float*)d_in[13];
  const float* Wv   = (const float*)d_in[14];
  const float* fcw  = (const float*)d_in[15];
  const float* fcb  = (const float*)d_in[16];
  const float* lnw  = (const float*)d_in[17];
  const float* lnb  = (const float*)d_in[18];
  float* out = (float*)d_out;

  char* w8 = (char*)d_ws;
  ushort* Gamma = (ushort*)(w8);                    //  8,388,608 (bf16, R17)
  float*  xm    = (float*)(w8 + 16777216);          // 12,582,912
  float*  psum  = (float*)(w8 + 29360128);          //    393,216
  ushort* xpeb  = (ushort*)(w8 + 29753344);         //  6,291,456 (bf16)
  ushort* Qb    = (ushort*)(w8 + 36044800);         // 16,777,216 (bf16, [b][h][q][dk])
  ushort* Kp    = (ushort*)(w8 + 52822016);         //  8,388,608 (bf16, [b][h][s][dk])
  ushort* Vt    = (ushort*)(w8 + 61210624);         //  8,388,608 (bf16, [b][h][dk][s])
  ushort* Ao    = (ushort*)(w8 + 69599232);         // 16,777,216 (bf16, [b][h][q][dk])
  ushort* fcwb  = (ushort*)(w8 + 86376448);         //    131,072 (bf16)
  ushort* Wgb   = (ushort*)(w8 + 105381888);        //     32,768 (bf16)
  ushort* Wqb   = (ushort*)(w8 + 105414656);        //    131,072 (bf16)
  ushort* Wkb   = (ushort*)(w8 + 105545728);        //     98,304 (bf16)
  ushort* Wvb   = (ushort*)(w8 + 105644032);        //     98,304 (bf16)
  // conv im2col scratch lives inside Ao's region (Ao written only later by
  // attn; conv stage finishes before attn runs — same-stream ordering)
  ushort* xvp   = (ushort*)(w8 + 69599232);         //  4,243,456 (bf16 hi+lo)
  ushort* wbigb = (ushort*)(w8 + 69599232 + 4243456); //  172,032 (bf16, [192][448])

  prep_kernel<<<240 + 4144 + 192 + 512, 256, 0, stream>>>(
      Wg, Wgb, Wq, Wqb, Wk, Wkb, Wv, Wvb, fcw, fcwb,
      x_velocity, xvp, w3, w5, w7, wbigb, remb, psum);

  conv_mfma_kernel<<<B * MN / 16, 256, 0, stream>>>(xvp, wbigb, b3, b5, b7, xm);
  pe4_kernel<<<(B * MN * 48) / 256, 256, 0, stream>>>(xm, psum, remb, dww, dwb, xpeb);

  proj_all3_kernel<<<1280, 256, 0, stream>>>(
      x_velocity, Wgb, Gamma, x_spatial, Wqb, Qb, xpeb, Wkb, Kp, Wvb, Vt);

  attn_mfma_kernel<<<B * NH * (L / 128), 256, 0, stream>>>(Qb, Kp, Vt, Ao);
  final2_mfma_kernel<<<B * L / 128, 256, 0, stream>>>(Ao, fcwb, fcb, Gamma,
                                                      x_spatial, lnw, lnb, out);
}